// Round 7
// baseline (312.387 us; speedup 1.0000x reference)
//
#include <hip/hip_runtime.h>
#include <hip/hip_bf16.h>
#include <math.h>

typedef __bf16 bf16;
typedef __bf16 bf16x8 __attribute__((ext_vector_type(8)));
typedef __bf16 bf16x4 __attribute__((ext_vector_type(4)));
typedef __bf16 bf16x2 __attribute__((ext_vector_type(2)));
typedef float  f32x4  __attribute__((ext_vector_type(4)));

#define D_MODEL 384
#define HID     1536
#define NSEQ    1024
#define ROWS    16384
#define HEADS   8
#define DH      48
#define SCALE   0.14433756729740643f // 48^-0.5
#define MFIX    8.0f                 // fixed softmax max (scores bounded ~6.5)
// bias table compressed by dist(dy,dx)=dist(-dy,dx): [|dy| 0..31][dx+31 0..62]
#define BT2_N   2016                 // 32*63 entries per head, f32
// packed KV tile geometry: [64 rows][72 cols] bf16 = 9216 B per tile
#define KVT     4608                 // elems per tile
#define QP_BH   (NSEQ * DH)          // 49152 elems per bh in Qpack
#define KP_BH   (16 * KVT)           // 73728 elems per bh in K/Vpack

__device__ __forceinline__ void gload16(const void* g, void* l) {
    __builtin_amdgcn_global_load_lds((const __attribute__((address_space(1))) void*)g,
                                     (__attribute__((address_space(3))) void*)l, 16, 0, 0);
}

// tanh-form GELU: max |err| vs exact erf-GELU ~1e-3 (below bf16 quantization)
__device__ __forceinline__ float fast_gelu(float x) {
    float u = 0.7978845608f * fmaf(0.044715f * x * x, x, x);
    float e = __expf(2.f * u);
    float t = 1.f - 2.f * __builtin_amdgcn_rcpf(e + 1.f);   // tanh(u)
    return 0.5f * x * (1.f + t);
}

// ---------------------------------------------------------------------------
// Mega prep kernel: blockIdx-switched fusion of
//   [0,432)      wtrans x4 (w_qkv, w_out, w1, w2)
//   [432,1072)   pack_init (Kpack pad cols, Vpack ones-rows)
//   [1072,1080)  bias_prep (compressed |dy| table, f32, -MFIX folded)
//   [1080,5176)  LN1 (x -> regB bf16)
// ---------------------------------------------------------------------------
__device__ __forceinline__ void wtrans_body(const float* __restrict__ in,
                                            bf16* __restrict__ out, int K, int N,
                                            int bx, int by, float (*T)[65])
{
    const int k0 = by * 64, n0 = bx * 64;
    const int rr = threadIdx.x >> 4, rc = threadIdx.x & 15;
#pragma unroll
    for (int i = 0; i < 4; ++i) {
        float4 v = *(const float4*)(in + (size_t)(k0 + rr + i * 16) * N + n0 + rc * 4);
        T[rr + i * 16][rc * 4 + 0] = v.x;  T[rr + i * 16][rc * 4 + 1] = v.y;
        T[rr + i * 16][rc * 4 + 2] = v.z;  T[rr + i * 16][rc * 4 + 3] = v.w;
    }
    __syncthreads();
#pragma unroll
    for (int i = 0; i < 4; ++i) {
        int n = rr + i * 16, kc = rc * 4;
        bf16x4 o;
        o[0] = (bf16)T[kc + 0][n];  o[1] = (bf16)T[kc + 1][n];
        o[2] = (bf16)T[kc + 2][n];  o[3] = (bf16)T[kc + 3][n];
        *(bf16x4*)(out + (size_t)(n0 + n) * K + k0 + kc) = o;
    }
}

__device__ __forceinline__ void ln_body(const float* __restrict__ x,
                                        const float* __restrict__ w,
                                        const float* __restrict__ b,
                                        bf16* __restrict__ out, int blk)
{
    int row  = blk * 4 + ((int)threadIdx.x >> 6);
    int lane = threadIdx.x & 63;
    const float* xr = x + (size_t)row * D_MODEL;

    float2 v[3];
    float s = 0.f, ss = 0.f;
#pragma unroll
    for (int i = 0; i < 3; ++i) {
        v[i] = *(const float2*)(xr + lane * 2 + i * 128);
        s  += v[i].x + v[i].y;
        ss += v[i].x * v[i].x + v[i].y * v[i].y;
    }
#pragma unroll
    for (int off = 32; off; off >>= 1) {
        s  += __shfl_xor(s,  off);
        ss += __shfl_xor(ss, off);
    }
    float mu   = s * (1.f / D_MODEL);
    float var  = ss * (1.f / D_MODEL) - mu * mu;
    float rstd = rsqrtf(var + 1e-5f);

    bf16* orow = out + (size_t)row * D_MODEL;
#pragma unroll
    for (int i = 0; i < 3; ++i) {
        int c = lane * 2 + i * 128;
        float2 wv = *(const float2*)(w + c);
        float2 bv = *(const float2*)(b + c);
        bf16x2 o;
        o[0] = (bf16)((v[i].x - mu) * rstd * wv.x + bv.x);
        o[1] = (bf16)((v[i].y - mu) * rstd * wv.y + bv.y);
        *(bf16x2*)(orow + c) = o;
    }
}

__global__ __launch_bounds__(256)
void prep_kernel(const float* __restrict__ w_qkv, const float* __restrict__ w_out,
                 const float* __restrict__ w1, const float* __restrict__ w2,
                 bf16* __restrict__ wqkvT, bf16* __restrict__ woutT,
                 bf16* __restrict__ w1T, bf16* __restrict__ w2T,
                 bf16* __restrict__ Kp, bf16* __restrict__ Vp,
                 const float* __restrict__ bias_table, float* __restrict__ Btab,
                 const float* __restrict__ x, const float* __restrict__ ln1_w,
                 const float* __restrict__ ln1_b, bf16* __restrict__ regB)
{
    __shared__ float T[64][65];
    const int bid = blockIdx.x, tid = threadIdx.x;

    if (bid < 432) {                       // ---- weight transposes
        const float* in; bf16* outp; int K, N, nx, local;
        if (bid < 108)      { in = w_qkv; outp = wqkvT; K = 384;  N = 1152; local = bid;       nx = 18; }
        else if (bid < 144) { in = w_out; outp = woutT; K = 384;  N = 384;  local = bid - 108; nx = 6;  }
        else if (bid < 288) { in = w1;    outp = w1T;   K = 384;  N = 1536; local = bid - 144; nx = 24; }
        else                { in = w2;    outp = w2T;   K = 1536; N = 384;  local = bid - 288; nx = 6;  }
        wtrans_body(in, outp, K, N, local % nx, local / nx, T);
    } else if (bid < 1072) {               // ---- pack init
        const int pb = bid - 432;
        if (pb < 512) {                    // 131072 K-rows, pad cols 48..71
            int row = pb * 256 + tid;
            bf16x8 z = {};
            bf16* p = Kp + (size_t)row * 72 + 48;
            *(bf16x8*)(p) = z;  *(bf16x8*)(p + 8) = z;  *(bf16x8*)(p + 16) = z;
        } else {                           // 32768 V ones-rows
            int idx = (pb - 512) * 256 + tid;
            int tile = idx >> 4, rr = idx & 15;
            bf16 o = (bf16)1.f;
            bf16x8 ones = {o, o, o, o, o, o, o, o};
            bf16* p = Vp + (size_t)tile * KVT + (48 + rr) * 72;
#pragma unroll
            for (int c = 0; c < 9; ++c) *(bf16x8*)(p + c * 8) = ones;
        }
    } else if (bid < 1080) {               // ---- bias prep (compressed, f32)
        int idx = (bid - 1072) * 256 + tid;
        if (idx < BT2_N) {
            int dy = idx / 63, dx = idx % 63 - 31;
            int s2 = dy * dy + dx * dx;
            int r = (int)ceilf(sqrtf((float)s2));
            while (r * r < s2) ++r;
            while (r > 0 && (r - 1) * (r - 1) >= s2) --r;
#pragma unroll
            for (int h = 0; h < HEADS; ++h)
                Btab[h * BT2_N + idx] = bias_table[r * HEADS + h] - MFIX;
        }
    } else {                               // ---- LN1
        ln_body(x, ln1_w, ln1_b, regB, bid - 1080);
    }
}

// ---------------------------------------------------------------------------
// LayerNorm standalone (LN2): 4 rows per 256-thread block.
// ---------------------------------------------------------------------------
__global__ __launch_bounds__(256)
void ln_kernel(const float* __restrict__ x, const float* __restrict__ w,
               const float* __restrict__ b, bf16* __restrict__ out)
{
    ln_body(x, w, b, out, blockIdx.x);
}

// ---------------------------------------------------------------------------
// GEMM: C[M,N] = A[M,K] @ BT[N,K]^T, bf16, 128x128 tile, BK=64, XCD swizzle.
// EPI 1: +bias +f32 res -> f32.  EPI 2: +bias, fast GELU -> bf16.
// EPI 3: scatter to packed Q/K/V attn layouts (SCALE folded into Q).
// ---------------------------------------------------------------------------
template<int EPI, typename CT>
__global__ __launch_bounds__(256)
void gemm3_kernel(const bf16* __restrict__ A, const bf16* __restrict__ BT,
                  CT* __restrict__ C, const float* __restrict__ bias,
                  const float* __restrict__ res, int nxblk, int Nn, int K,
                  bf16* __restrict__ qp, bf16* __restrict__ kp, bf16* __restrict__ vp)
{
    __shared__ alignas(16) bf16 As[128][64];
    __shared__ alignas(16) bf16 Bs[128][64];

    const int bid  = blockIdx.x;
    const int xcd  = bid & 7;
    const int slot = bid >> 3;
    const int yy   = slot / nxblk;
    const int m0   = (yy * 8 + xcd) * 128;
    const int n0   = (slot - yy * nxblk) * 128;

    const int tid  = threadIdx.x;
    const int w    = tid >> 6;
    const int lane = tid & 63;
    const int quad = lane >> 4;
    const int l16  = lane & 15;

    const int srow = lane >> 3;          // 0..7
    const int scol = (lane & 7) * 8;     // 0..56

    f32x4 acc[4][4] = {};

    for (int kt = 0; kt < K; kt += 64) {
        __syncthreads();
#pragma unroll
        for (int c = 0; c < 4; ++c) {
            const int ch = w * 4 + c;
            gload16(A  + (size_t)(m0 + ch * 8 + srow) * K + kt + scol, &As[ch * 8][0]);
            gload16(BT + (size_t)(n0 + ch * 8 + srow) * K + kt + scol, &Bs[ch * 8][0]);
        }
        __syncthreads();

#pragma unroll
        for (int kk = 0; kk < 2; ++kk) {
            bf16x8 af[4], bfr[4];
#pragma unroll
            for (int mt = 0; mt < 4; ++mt)
                af[mt] = *(const bf16x8*)(&As[(w & 1) * 64 + mt * 16 + l16][kk * 32 + quad * 8]);
#pragma unroll
            for (int nt = 0; nt < 4; ++nt)
                bfr[nt] = *(const bf16x8*)(&Bs[(w >> 1) * 64 + nt * 16 + l16][kk * 32 + quad * 8]);
#pragma unroll
            for (int mt = 0; mt < 4; ++mt)
#pragma unroll
                for (int nt = 0; nt < 4; ++nt)
                    acc[mt][nt] = __builtin_amdgcn_mfma_f32_16x16x32_bf16(
                        af[mt], bfr[nt], acc[mt][nt], 0, 0, 0);
        }
    }

#pragma unroll
    for (int mt = 0; mt < 4; ++mt) {
#pragma unroll
        for (int nt = 0; nt < 4; ++nt) {
            const int c0 = n0 + (w >> 1) * 64 + nt * 16;   // wave-uniform
            const int c  = c0 + l16;
            float bi = (EPI == 1 || EPI == 2) ? bias[c] : 0.f;
#pragma unroll
            for (int r = 0; r < 4; ++r) {
                int row = m0 + (w & 1) * 64 + mt * 16 + quad * 4 + r;
                float v = acc[mt][nt][r] + bi;
                if (EPI == 1) {
                    v += res[(size_t)row * Nn + c];
                    C[(size_t)row * Nn + c] = (CT)v;
                } else if (EPI == 2) {
                    v = fast_gelu(v);
                    C[(size_t)row * Nn + c] = (CT)v;
                } else { // EPI 3: packed QKV scatter
                    int b   = row >> 10, seq = row & 1023;
                    if (c0 < 384) {            // Q (scaled)
                        int h = c / 48, d = c - h * 48;
                        qp[(size_t)(b * 8 + h) * QP_BH + seq * 48 + d] = (bf16)(v * SCALE);
                    } else if (c0 < 768) {     // K
                        int ck = c - 384;
                        int h = ck / 48, d = ck - h * 48;
                        kp[(size_t)(b * 8 + h) * KP_BH + (seq >> 6) * KVT
                           + (seq & 63) * 72 + d] = (bf16)v;
                    } else {                   // V transposed
                        int cv = c - 768;
                        int h = cv / 48, d = cv - h * 48;
                        vp[(size_t)(b * 8 + h) * KP_BH + (seq >> 6) * KVT
                           + d * 72 + (seq & 63)] = (bf16)v;
                    }
                }
            }
        }
    }
}

// ---------------------------------------------------------------------------
// MFMA flash attention v9: verified r6 per-tile compute body (KVBLK=64,
// compressed f32 bias table), now with DOUBLE-BUFFERED K/V staging and
// counted vmcnt: tile t+1's global_load_lds are issued before computing
// tile t, and we wait only vmcnt(3) (t's loads done; t+1's stay in flight
// across raw s_barrier). No __syncthreads in the loop -> no vmcnt(0) drain.
// Staging: 18 x 1KB chunks, waves 0..5 issue exactly 3 each (uniform count
// so the vmcnt literal is exact); waves 6,7 issue none.
// LDS = 2*18432 + 36864 + 8064 = 81792 B -> 2 blocks/CU.
// ---------------------------------------------------------------------------
__global__ __launch_bounds__(512)
void attn_kernel(const bf16* __restrict__ Qp, const bf16* __restrict__ Kp,
                 const bf16* __restrict__ Vp, const float* __restrict__ Btab,
                 bf16* __restrict__ out)
{
    __shared__ alignas(16) bf16 Ks[2][64][72];     // [buf][key][dh pad64]
    __shared__ alignas(16) bf16 Vs[2][64][72];     // [buf][dh][key]; rows 48..63 ones
    __shared__ alignas(16) bf16 Ps[8][2][16][72];  // [wave][strip][query][key]
    __shared__ alignas(16) float B2f[BT2_N];       // compressed bias, f32

    const int bid  = blockIdx.x;
    const int xcd  = bid & 7;
    const int slot = bid >> 3;                     // 0..63
    const int qc   = slot & 3;                     // 4 q-blocks of 256 rows
    const int bh   = (slot >> 2) * 8 + xcd;        // 0..127, all qc of bh on one XCD
    const int q0   = qc * 256;
    const int tid  = threadIdx.x;
    const int wave = tid >> 6;                     // 0..7
    const int lane = tid & 63;
    const int quad = lane >> 4;
    const int l16  = lane & 15;
    const int b    = bh >> 3, h = bh & 7;

    // stage compressed bias table (8064 B): one gload16 for threads 0..503
    {
        const char* src = (const char*)(Btab + (size_t)h * BT2_N);
        int off = tid * 16;
        if (off < BT2_N * 4)
            gload16(src + off, (char*)B2f + wave * 1024);
    }

    // Q fragments for 2 strips (B-operand), SCALE pre-applied in Qpack
    bf16x8 qf0[2], qf1[2];
    int qy[2], qxp[2];
#pragma unroll
    for (int s = 0; s < 2; ++s) {
        int qrow = q0 + s * 128 + wave * 16 + l16;
        const bf16* qptr = Qp + (size_t)bh * QP_BH + qrow * 48;
        qf0[s] = *(const bf16x8*)(qptr + quad * 8);
#pragma unroll
        for (int c = 0; c < 8; ++c) qf1[s][c] = (bf16)0.f;
        if (quad < 2) qf1[s] = *(const bf16x8*)(qptr + 32 + quad * 8);
        qy[s]  = qrow >> 5;
        qxp[s] = (qrow & 31) + 31;
    }

    f32x4 o_acc[2][4] = {};   // [strip][0..2 = O dims, 3 = l]

    // async stage of tile tt into buffer bufsel: waves 0..5, 3 chunks each
    auto STAGE = [&](int tt, int bufsel) {
        if (wave < 6) {
            const bf16* kb = Kp + (size_t)(bh * 16 + tt) * KVT;
            const bf16* vb = Vp + (size_t)(bh * 16 + tt) * KVT;
#pragma unroll
            for (int j = 0; j < 3; ++j) {
                int i = wave * 3 + j;
                if (i < 9) gload16(kb + i * 512 + lane * 8,
                                   (bf16*)&Ks[bufsel][0][0] + i * 512);
                else       gload16(vb + (i - 9) * 512 + lane * 8,
                                   (bf16*)&Vs[bufsel][0][0] + (i - 9) * 512);
            }
        }
    };

    STAGE(0, 0);   // prologue

    for (int t = 0; t < 16; ++t) {
        const int cur = t & 1;
        if (t < 15) {
            STAGE(t + 1, cur ^ 1);
            asm volatile("s_waitcnt vmcnt(3)" ::: "memory");   // tile t landed
        } else {
            asm volatile("s_waitcnt vmcnt(0)" ::: "memory");
        }
        __builtin_amdgcn_s_barrier();            // all waves: buf[cur] ready
        __builtin_amdgcn_sched_barrier(0);

        const int n0 = t * 64;

        // S^T = K @ Q^T: D[key=quad*4+r][query=l16], K-frags shared by strips
        f32x4 sa[2][4] = {};
#pragma unroll
        for (int nt = 0; nt < 4; ++nt) {
            bf16x8 a0 = *(const bf16x8*)(&Ks[cur][nt * 16 + l16][quad * 8]);
            bf16x8 a1 = *(const bf16x8*)(&Ks[cur][nt * 16 + l16][32 + quad * 8]);
#pragma unroll
            for (int s = 0; s < 2; ++s) {
                sa[s][nt] = __builtin_amdgcn_mfma_f32_16x16x32_bf16(a0, qf0[s], sa[s][nt], 0, 0, 0);
                sa[s][nt] = __builtin_amdgcn_mfma_f32_16x16x32_bf16(a1, qf1[s], sa[s][nt], 0, 0, 0);
            }
        }

        // p = exp(s + bias - MFIX), |dy|-folded table index
#pragma unroll
        for (int s = 0; s < 2; ++s)
#pragma unroll
            for (int nt = 0; nt < 4; ++nt) {
                const int j0 = n0 + nt * 16 + quad * 4;
                int dy  = qy[s] - (j0 >> 5);
                int iay = dy < 0 ? -dy : dy;
                const int ib0 = iay * 63 + qxp[s] - (j0 & 31);
                bf16x4 pk;
#pragma unroll
                for (int r = 0; r < 4; ++r)
                    pk[r] = (bf16)__expf(sa[s][nt][r] + B2f[ib0 - r]);
                *(bf16x4*)(&Ps[wave][s][l16][nt * 16 + quad * 4]) = pk;
            }

        // O += P @ V; V-frags shared by strips; d=3 row accumulates l
#pragma unroll
        for (int kk = 0; kk < 2; ++kk) {
            bf16x8 vf[4];
#pragma unroll
            for (int d = 0; d < 4; ++d)
                vf[d] = *(const bf16x8*)(&Vs[cur][d * 16 + l16][kk * 32 + quad * 8]);
#pragma unroll
            for (int s = 0; s < 2; ++s) {
                bf16x8 pf = *(const bf16x8*)(&Ps[wave][s][l16][kk * 32 + quad * 8]);
#pragma unroll
                for (int d = 0; d < 4; ++d)
                    o_acc[s][d] = __builtin_amdgcn_mfma_f32_16x16x32_bf16(
                        pf, vf[d], o_acc[s][d], 0, 0, 0);
            }
        }

        __builtin_amdgcn_s_barrier();   // protect buf[cur] from next STAGE
    }

    // epilogue
#pragma unroll
    for (int s = 0; s < 2; ++s)
#pragma unroll
        for (int r = 0; r < 4; ++r) {
            float inv = 1.f / o_acc[s][3][r];
            int row = q0 + s * 128 + wave * 16 + quad * 4 + r;
            bf16* orow = out + ((size_t)b * NSEQ + row) * D_MODEL + h * DH;
#pragma unroll
            for (int d = 0; d < 3; ++d)
                orow[d * 16 + l16] = (bf16)(o_acc[s][d][r] * inv);
        }
}

// ---------------------------------------------------------------------------
extern "C" void kernel_launch(void* const* d_in, const int* in_sizes, int n_in,
                              void* d_out, int out_size, void* d_ws, size_t ws_size,
                              hipStream_t stream)
{
    const float* x          = (const float*)d_in[0];
    const float* ln1_w      = (const float*)d_in[1];
    const float* ln1_b      = (const float*)d_in[2];
    const float* w_qkv      = (const float*)d_in[3];
    const float* bias_table = (const float*)d_in[4];
    const float* w_out      = (const float*)d_in[5];
    const float* b_out      = (const float*)d_in[6];
    const float* ln2_w      = (const float*)d_in[7];
    const float* ln2_b      = (const float*)d_in[8];
    const float* w1         = (const float*)d_in[9];
    const float* b1         = (const float*)d_in[10];
    const float* w2         = (const float*)d_in[11];
    const float* b2         = (const float*)d_in[12];
    float* out = (float*)d_out;

    bf16* regA  = (bf16*)d_ws;                    // 25.17M elems: packs, later gelu
    bf16* Qpack = regA;                           // [128][1024][48]     6.29M
    bf16* Kpack = regA + 6291456;                 // [128][16][64][72]   9.44M
    bf16* Vpack = regA + 15728640;                // [128][16][64][72]   9.44M
    bf16* regB  = regA + (size_t)ROWS * HID;      // [16384][384]
    bf16* wqkvT = regB + (size_t)ROWS * D_MODEL;  // [1152][384]
    bf16* woutT = wqkvT + 1152 * 384;             // [384][384]
    bf16* w1T   = woutT + 384 * 384;              // [1536][384]
    bf16* w2T   = w1T + 1536 * 384;               // [384][1536]
    float* Btab = (float*)(w2T + 384 * 1536);     // [8][2016] f32 compressed
    float* x1   = out;                            // residual in d_out (f32)

    // 0. fused prep: wtrans x4 + pack_init + bias_prep + LN1
    prep_kernel<<<5176, 256, 0, stream>>>(
        w_qkv, w_out, w1, w2, wqkvT, woutT, w1T, w2T,
        Kpack, Vpack, bias_table, Btab, x, ln1_w, ln1_b, regB);
    // 2. qkv GEMM -> packed Q/K/V (EPI3)
    gemm3_kernel<3, bf16><<<(1152 / 128) * (ROWS / 128), 256, 0, stream>>>(
        regB, wqkvT, (bf16*)nullptr, nullptr, nullptr, 1152 / 128, 1152, D_MODEL,
        Qpack, Kpack, Vpack);
    // 3. attention -> regB  (512 blocks x 512 threads; 2 blocks/CU exactly)
    attn_kernel<<<512, 512, 0, stream>>>(Qpack, Kpack, Vpack, Btab, regB);
    // 4. x1 = attn @ w_out + b_out + x -> d_out (f32)
    gemm3_kernel<1, float><<<(D_MODEL / 128) * (ROWS / 128), 256, 0, stream>>>(
        regB, woutT, x1, b_out, x, D_MODEL / 128, D_MODEL, D_MODEL,
        nullptr, nullptr, nullptr);
    // 5. LN2 -> regB
    ln_kernel<<<ROWS / 4, 256, 0, stream>>>(x1, ln2_w, ln2_b, regB);
    // 6. gelu(h2 @ w1 + b1) -> regA (packs dead now)
    gemm3_kernel<2, bf16><<<(HID / 128) * (ROWS / 128), 256, 0, stream>>>(
        regB, w1T, regA, b1, nullptr, HID / 128, HID, D_MODEL,
        nullptr, nullptr, nullptr);
    // 7. out = gelu @ w2 + b2 + x1
    gemm3_kernel<1, float><<<(D_MODEL / 128) * (ROWS / 128), 256, 0, stream>>>(
        regA, w2T, out, b2, x1, D_MODEL / 128, D_MODEL, HID,
        nullptr, nullptr, nullptr);
}

// Round 8
// 297.961 us; speedup vs baseline: 1.0484x; 1.0484x over previous
//
#include <hip/hip_runtime.h>
#include <hip/hip_bf16.h>
#include <math.h>

typedef __bf16 bf16;
typedef __bf16 bf16x8 __attribute__((ext_vector_type(8)));
typedef __bf16 bf16x4 __attribute__((ext_vector_type(4)));
typedef __bf16 bf16x2 __attribute__((ext_vector_type(2)));
typedef float  f32x4  __attribute__((ext_vector_type(4)));

#define D_MODEL 384
#define HID     1536
#define NSEQ    1024
#define ROWS    16384
#define HEADS   8
#define DH      48
#define SCALE   0.14433756729740643f // 48^-0.5
#define MFIX    8.0f                 // fixed softmax max (scores bounded ~6.5)
// bias table compressed by dist(dy,dx)=dist(-dy,dx): [|dy| 0..31][dx+31 0..62]
#define BT2_N   2016                 // 32*63 entries per head, f32
// packed KV tile geometry: [64 rows][72 cols] bf16 = 9216 B per tile
#define KVT     4608                 // elems per tile
#define QP_BH   (NSEQ * DH)          // 49152 elems per bh in Qpack
#define KP_BH   (16 * KVT)           // 73728 elems per bh in K/Vpack

__device__ __forceinline__ void gload16(const void* g, void* l) {
    __builtin_amdgcn_global_load_lds((const __attribute__((address_space(1))) void*)g,
                                     (__attribute__((address_space(3))) void*)l, 16, 0, 0);
}

// tanh-form GELU: max |err| vs exact erf-GELU ~1e-3 (below bf16 quantization)
__device__ __forceinline__ float fast_gelu(float x) {
    float u = 0.7978845608f * fmaf(0.044715f * x * x, x, x);
    float e = __expf(2.f * u);
    float t = 1.f - 2.f * __builtin_amdgcn_rcpf(e + 1.f);   // tanh(u)
    return 0.5f * x * (1.f + t);
}

// ---------------------------------------------------------------------------
// Mega prep kernel: blockIdx-switched fusion of
//   [0,432)      wtrans x4 (w_qkv, w_out, w1, w2)
//   [432,1072)   pack_init (Kpack pad cols, Vpack ones-rows)
//   [1072,1080)  bias_prep (compressed |dy| table, f32, -MFIX folded)
//   [1080,5176)  LN1 (x -> regB bf16)
// ---------------------------------------------------------------------------
__device__ __forceinline__ void wtrans_body(const float* __restrict__ in,
                                            bf16* __restrict__ out, int K, int N,
                                            int bx, int by, float (*T)[65])
{
    const int k0 = by * 64, n0 = bx * 64;
    const int rr = threadIdx.x >> 4, rc = threadIdx.x & 15;
#pragma unroll
    for (int i = 0; i < 4; ++i) {
        float4 v = *(const float4*)(in + (size_t)(k0 + rr + i * 16) * N + n0 + rc * 4);
        T[rr + i * 16][rc * 4 + 0] = v.x;  T[rr + i * 16][rc * 4 + 1] = v.y;
        T[rr + i * 16][rc * 4 + 2] = v.z;  T[rr + i * 16][rc * 4 + 3] = v.w;
    }
    __syncthreads();
#pragma unroll
    for (int i = 0; i < 4; ++i) {
        int n = rr + i * 16, kc = rc * 4;
        bf16x4 o;
        o[0] = (bf16)T[kc + 0][n];  o[1] = (bf16)T[kc + 1][n];
        o[2] = (bf16)T[kc + 2][n];  o[3] = (bf16)T[kc + 3][n];
        *(bf16x4*)(out + (size_t)(n0 + n) * K + k0 + kc) = o;
    }
}

__device__ __forceinline__ void ln_body(const float* __restrict__ x,
                                        const float* __restrict__ w,
                                        const float* __restrict__ b,
                                        bf16* __restrict__ out, int blk)
{
    int row  = blk * 4 + ((int)threadIdx.x >> 6);
    int lane = threadIdx.x & 63;
    const float* xr = x + (size_t)row * D_MODEL;

    float2 v[3];
    float s = 0.f, ss = 0.f;
#pragma unroll
    for (int i = 0; i < 3; ++i) {
        v[i] = *(const float2*)(xr + lane * 2 + i * 128);
        s  += v[i].x + v[i].y;
        ss += v[i].x * v[i].x + v[i].y * v[i].y;
    }
#pragma unroll
    for (int off = 32; off; off >>= 1) {
        s  += __shfl_xor(s,  off);
        ss += __shfl_xor(ss, off);
    }
    float mu   = s * (1.f / D_MODEL);
    float var  = ss * (1.f / D_MODEL) - mu * mu;
    float rstd = rsqrtf(var + 1e-5f);

    bf16* orow = out + (size_t)row * D_MODEL;
#pragma unroll
    for (int i = 0; i < 3; ++i) {
        int c = lane * 2 + i * 128;
        float2 wv = *(const float2*)(w + c);
        float2 bv = *(const float2*)(b + c);
        bf16x2 o;
        o[0] = (bf16)((v[i].x - mu) * rstd * wv.x + bv.x);
        o[1] = (bf16)((v[i].y - mu) * rstd * wv.y + bv.y);
        *(bf16x2*)(orow + c) = o;
    }
}

__global__ __launch_bounds__(256)
void prep_kernel(const float* __restrict__ w_qkv, const float* __restrict__ w_out,
                 const float* __restrict__ w1, const float* __restrict__ w2,
                 bf16* __restrict__ wqkvT, bf16* __restrict__ woutT,
                 bf16* __restrict__ w1T, bf16* __restrict__ w2T,
                 bf16* __restrict__ Kp, bf16* __restrict__ Vp,
                 const float* __restrict__ bias_table, float* __restrict__ Btab,
                 const float* __restrict__ x, const float* __restrict__ ln1_w,
                 const float* __restrict__ ln1_b, bf16* __restrict__ regB)
{
    __shared__ float T[64][65];
    const int bid = blockIdx.x, tid = threadIdx.x;

    if (bid < 432) {                       // ---- weight transposes
        const float* in; bf16* outp; int K, N, nx, local;
        if (bid < 108)      { in = w_qkv; outp = wqkvT; K = 384;  N = 1152; local = bid;       nx = 18; }
        else if (bid < 144) { in = w_out; outp = woutT; K = 384;  N = 384;  local = bid - 108; nx = 6;  }
        else if (bid < 288) { in = w1;    outp = w1T;   K = 384;  N = 1536; local = bid - 144; nx = 24; }
        else                { in = w2;    outp = w2T;   K = 1536; N = 384;  local = bid - 288; nx = 6;  }
        wtrans_body(in, outp, K, N, local % nx, local / nx, T);
    } else if (bid < 1072) {               // ---- pack init
        const int pb = bid - 432;
        if (pb < 512) {                    // 131072 K-rows, pad cols 48..71
            int row = pb * 256 + tid;
            bf16x8 z = {};
            bf16* p = Kp + (size_t)row * 72 + 48;
            *(bf16x8*)(p) = z;  *(bf16x8*)(p + 8) = z;  *(bf16x8*)(p + 16) = z;
        } else {                           // 32768 V ones-rows
            int idx = (pb - 512) * 256 + tid;
            int tile = idx >> 4, rr = idx & 15;
            bf16 o = (bf16)1.f;
            bf16x8 ones = {o, o, o, o, o, o, o, o};
            bf16* p = Vp + (size_t)tile * KVT + (48 + rr) * 72;
#pragma unroll
            for (int c = 0; c < 9; ++c) *(bf16x8*)(p + c * 8) = ones;
        }
    } else if (bid < 1080) {               // ---- bias prep (compressed, f32)
        int idx = (bid - 1072) * 256 + tid;
        if (idx < BT2_N) {
            int dy = idx / 63, dx = idx % 63 - 31;
            int s2 = dy * dy + dx * dx;
            int r = (int)ceilf(sqrtf((float)s2));
            while (r * r < s2) ++r;
            while (r > 0 && (r - 1) * (r - 1) >= s2) --r;
#pragma unroll
            for (int h = 0; h < HEADS; ++h)
                Btab[h * BT2_N + idx] = bias_table[r * HEADS + h] - MFIX;
        }
    } else {                               // ---- LN1
        ln_body(x, ln1_w, ln1_b, regB, bid - 1080);
    }
}

// ---------------------------------------------------------------------------
// LayerNorm standalone (LN2): 4 rows per 256-thread block.
// ---------------------------------------------------------------------------
__global__ __launch_bounds__(256)
void ln_kernel(const float* __restrict__ x, const float* __restrict__ w,
               const float* __restrict__ b, bf16* __restrict__ out)
{
    ln_body(x, w, b, out, blockIdx.x);
}

// ---------------------------------------------------------------------------
// GEMM: C[M,N] = A[M,K] @ BT[N,K]^T, bf16, 128x128 tile, BK=64, XCD swizzle.
// v2: double-buffered LDS staging with counted vmcnt (attn-v9 pipeline):
// tile t+1's 8 global_load_lds per wave are issued before computing tile t;
// wait only vmcnt(8) so t+1's loads stay in flight across raw s_barrier.
// No __syncthreads in the K-loop -> no full vmcnt(0) drain per K-step.
// EPI 1: +bias +f32 res -> f32.  EPI 2: +bias, fast GELU -> bf16.
// EPI 3: scatter to packed Q/K/V attn layouts (SCALE folded into Q).
// ---------------------------------------------------------------------------
template<int EPI, typename CT>
__global__ __launch_bounds__(256)
void gemm3_kernel(const bf16* __restrict__ A, const bf16* __restrict__ BT,
                  CT* __restrict__ C, const float* __restrict__ bias,
                  const float* __restrict__ res, int nxblk, int Nn, int K,
                  bf16* __restrict__ qp, bf16* __restrict__ kp, bf16* __restrict__ vp)
{
    __shared__ alignas(16) bf16 As[2][128][64];
    __shared__ alignas(16) bf16 Bs[2][128][64];

    const int bid  = blockIdx.x;
    const int xcd  = bid & 7;
    const int slot = bid >> 3;
    const int yy   = slot / nxblk;
    const int m0   = (yy * 8 + xcd) * 128;
    const int n0   = (slot - yy * nxblk) * 128;

    const int tid  = threadIdx.x;
    const int w    = tid >> 6;
    const int lane = tid & 63;
    const int quad = lane >> 4;
    const int l16  = lane & 15;

    const int srow = lane >> 3;          // 0..7
    const int scol = (lane & 7) * 8;     // 0..56

    f32x4 acc[4][4] = {};
    const int nst = K >> 6;

    // stage K-tile tt into buffer bufsel: every wave issues exactly 8 loads
    auto STAGE = [&](int tt, int bufsel) {
#pragma unroll
        for (int c = 0; c < 4; ++c) {
            const int ch = w * 4 + c;
            gload16(A  + (size_t)(m0 + ch * 8 + srow) * K + tt * 64 + scol,
                    &As[bufsel][ch * 8][0]);
            gload16(BT + (size_t)(n0 + ch * 8 + srow) * K + tt * 64 + scol,
                    &Bs[bufsel][ch * 8][0]);
        }
    };

    STAGE(0, 0);   // prologue

    for (int t = 0; t < nst; ++t) {
        const int cur = t & 1;
        if (t + 1 < nst) {
            STAGE(t + 1, cur ^ 1);
            asm volatile("s_waitcnt vmcnt(8)" ::: "memory");   // tile t landed
        } else {
            asm volatile("s_waitcnt vmcnt(0)" ::: "memory");
        }
        __builtin_amdgcn_s_barrier();            // all waves: buf[cur] ready
        __builtin_amdgcn_sched_barrier(0);

#pragma unroll
        for (int kk = 0; kk < 2; ++kk) {
            bf16x8 af[4], bfr[4];
#pragma unroll
            for (int mt = 0; mt < 4; ++mt)
                af[mt] = *(const bf16x8*)(&As[cur][(w & 1) * 64 + mt * 16 + l16][kk * 32 + quad * 8]);
#pragma unroll
            for (int nt = 0; nt < 4; ++nt)
                bfr[nt] = *(const bf16x8*)(&Bs[cur][(w >> 1) * 64 + nt * 16 + l16][kk * 32 + quad * 8]);
#pragma unroll
            for (int mt = 0; mt < 4; ++mt)
#pragma unroll
                for (int nt = 0; nt < 4; ++nt)
                    acc[mt][nt] = __builtin_amdgcn_mfma_f32_16x16x32_bf16(
                        af[mt], bfr[nt], acc[mt][nt], 0, 0, 0);
        }

        __builtin_amdgcn_s_barrier();   // protect buf[cur] from next STAGE
    }

#pragma unroll
    for (int mt = 0; mt < 4; ++mt) {
#pragma unroll
        for (int nt = 0; nt < 4; ++nt) {
            const int c0 = n0 + (w >> 1) * 64 + nt * 16;   // wave-uniform
            const int c  = c0 + l16;
            float bi = (EPI == 1 || EPI == 2) ? bias[c] : 0.f;
#pragma unroll
            for (int r = 0; r < 4; ++r) {
                int row = m0 + (w & 1) * 64 + mt * 16 + quad * 4 + r;
                float v = acc[mt][nt][r] + bi;
                if (EPI == 1) {
                    v += res[(size_t)row * Nn + c];
                    C[(size_t)row * Nn + c] = (CT)v;
                } else if (EPI == 2) {
                    v = fast_gelu(v);
                    C[(size_t)row * Nn + c] = (CT)v;
                } else { // EPI 3: packed QKV scatter
                    int b   = row >> 10, seq = row & 1023;
                    if (c0 < 384) {            // Q (scaled)
                        int h = c / 48, d = c - h * 48;
                        qp[(size_t)(b * 8 + h) * QP_BH + seq * 48 + d] = (bf16)(v * SCALE);
                    } else if (c0 < 768) {     // K
                        int ck = c - 384;
                        int h = ck / 48, d = ck - h * 48;
                        kp[(size_t)(b * 8 + h) * KP_BH + (seq >> 6) * KVT
                           + (seq & 63) * 72 + d] = (bf16)v;
                    } else {                   // V transposed
                        int cv = c - 768;
                        int h = cv / 48, d = cv - h * 48;
                        vp[(size_t)(b * 8 + h) * KP_BH + (seq >> 6) * KVT
                           + d * 72 + (seq & 63)] = (bf16)v;
                    }
                }
            }
        }
    }
}

// ---------------------------------------------------------------------------
// MFMA flash attention v9 (verified r7): KVBLK=64, compressed f32 bias table,
// double-buffered K/V staging with counted vmcnt + raw s_barrier.
// Staging: 18 x 1KB chunks, waves 0..5 issue exactly 3 each; vmcnt(3).
// LDS = 2*18432 + 36864 + 8064 = 81792 B -> 2 blocks/CU.
// ---------------------------------------------------------------------------
__global__ __launch_bounds__(512)
void attn_kernel(const bf16* __restrict__ Qp, const bf16* __restrict__ Kp,
                 const bf16* __restrict__ Vp, const float* __restrict__ Btab,
                 bf16* __restrict__ out)
{
    __shared__ alignas(16) bf16 Ks[2][64][72];     // [buf][key][dh pad64]
    __shared__ alignas(16) bf16 Vs[2][64][72];     // [buf][dh][key]; rows 48..63 ones
    __shared__ alignas(16) bf16 Ps[8][2][16][72];  // [wave][strip][query][key]
    __shared__ alignas(16) float B2f[BT2_N];       // compressed bias, f32

    const int bid  = blockIdx.x;
    const int xcd  = bid & 7;
    const int slot = bid >> 3;                     // 0..63
    const int qc   = slot & 3;                     // 4 q-blocks of 256 rows
    const int bh   = (slot >> 2) * 8 + xcd;        // 0..127, all qc of bh on one XCD
    const int q0   = qc * 256;
    const int tid  = threadIdx.x;
    const int wave = tid >> 6;                     // 0..7
    const int lane = tid & 63;
    const int quad = lane >> 4;
    const int l16  = lane & 15;
    const int b    = bh >> 3, h = bh & 7;

    // stage compressed bias table (8064 B): one gload16 for threads 0..503
    {
        const char* src = (const char*)(Btab + (size_t)h * BT2_N);
        int off = tid * 16;
        if (off < BT2_N * 4)
            gload16(src + off, (char*)B2f + wave * 1024);
    }

    // Q fragments for 2 strips (B-operand), SCALE pre-applied in Qpack
    bf16x8 qf0[2], qf1[2];
    int qy[2], qxp[2];
#pragma unroll
    for (int s = 0; s < 2; ++s) {
        int qrow = q0 + s * 128 + wave * 16 + l16;
        const bf16* qptr = Qp + (size_t)bh * QP_BH + qrow * 48;
        qf0[s] = *(const bf16x8*)(qptr + quad * 8);
#pragma unroll
        for (int c = 0; c < 8; ++c) qf1[s][c] = (bf16)0.f;
        if (quad < 2) qf1[s] = *(const bf16x8*)(qptr + 32 + quad * 8);
        qy[s]  = qrow >> 5;
        qxp[s] = (qrow & 31) + 31;
    }

    f32x4 o_acc[2][4] = {};   // [strip][0..2 = O dims, 3 = l]

    // async stage of tile tt into buffer bufsel: waves 0..5, 3 chunks each
    auto STAGE = [&](int tt, int bufsel) {
        if (wave < 6) {
            const bf16* kb = Kp + (size_t)(bh * 16 + tt) * KVT;
            const bf16* vb = Vp + (size_t)(bh * 16 + tt) * KVT;
#pragma unroll
            for (int j = 0; j < 3; ++j) {
                int i = wave * 3 + j;
                if (i < 9) gload16(kb + i * 512 + lane * 8,
                                   (bf16*)&Ks[bufsel][0][0] + i * 512);
                else       gload16(vb + (i - 9) * 512 + lane * 8,
                                   (bf16*)&Vs[bufsel][0][0] + (i - 9) * 512);
            }
        }
    };

    STAGE(0, 0);   // prologue

    for (int t = 0; t < 16; ++t) {
        const int cur = t & 1;
        if (t < 15) {
            STAGE(t + 1, cur ^ 1);
            asm volatile("s_waitcnt vmcnt(3)" ::: "memory");   // tile t landed
        } else {
            asm volatile("s_waitcnt vmcnt(0)" ::: "memory");
        }
        __builtin_amdgcn_s_barrier();            // all waves: buf[cur] ready
        __builtin_amdgcn_sched_barrier(0);

        const int n0 = t * 64;

        // S^T = K @ Q^T: D[key=quad*4+r][query=l16], K-frags shared by strips
        f32x4 sa[2][4] = {};
#pragma unroll
        for (int nt = 0; nt < 4; ++nt) {
            bf16x8 a0 = *(const bf16x8*)(&Ks[cur][nt * 16 + l16][quad * 8]);
            bf16x8 a1 = *(const bf16x8*)(&Ks[cur][nt * 16 + l16][32 + quad * 8]);
#pragma unroll
            for (int s = 0; s < 2; ++s) {
                sa[s][nt] = __builtin_amdgcn_mfma_f32_16x16x32_bf16(a0, qf0[s], sa[s][nt], 0, 0, 0);
                sa[s][nt] = __builtin_amdgcn_mfma_f32_16x16x32_bf16(a1, qf1[s], sa[s][nt], 0, 0, 0);
            }
        }

        // p = exp(s + bias - MFIX), |dy|-folded table index
#pragma unroll
        for (int s = 0; s < 2; ++s)
#pragma unroll
            for (int nt = 0; nt < 4; ++nt) {
                const int j0 = n0 + nt * 16 + quad * 4;
                int dy  = qy[s] - (j0 >> 5);
                int iay = dy < 0 ? -dy : dy;
                const int ib0 = iay * 63 + qxp[s] - (j0 & 31);
                bf16x4 pk;
#pragma unroll
                for (int r = 0; r < 4; ++r)
                    pk[r] = (bf16)__expf(sa[s][nt][r] + B2f[ib0 - r]);
                *(bf16x4*)(&Ps[wave][s][l16][nt * 16 + quad * 4]) = pk;
            }

        // O += P @ V; V-frags shared by strips; d=3 row accumulates l
#pragma unroll
        for (int kk = 0; kk < 2; ++kk) {
            bf16x8 vf[4];
#pragma unroll
            for (int d = 0; d < 4; ++d)
                vf[d] = *(const bf16x8*)(&Vs[cur][d * 16 + l16][kk * 32 + quad * 8]);
#pragma unroll
            for (int s = 0; s < 2; ++s) {
                bf16x8 pf = *(const bf16x8*)(&Ps[wave][s][l16][kk * 32 + quad * 8]);
#pragma unroll
                for (int d = 0; d < 4; ++d)
                    o_acc[s][d] = __builtin_amdgcn_mfma_f32_16x16x32_bf16(
                        pf, vf[d], o_acc[s][d], 0, 0, 0);
            }
        }

        __builtin_amdgcn_s_barrier();   // protect buf[cur] from next STAGE
    }

    // epilogue
#pragma unroll
    for (int s = 0; s < 2; ++s)
#pragma unroll
        for (int r = 0; r < 4; ++r) {
            float inv = 1.f / o_acc[s][3][r];
            int row = q0 + s * 128 + wave * 16 + quad * 4 + r;
            bf16* orow = out + ((size_t)b * NSEQ + row) * D_MODEL + h * DH;
#pragma unroll
            for (int d = 0; d < 3; ++d)
                orow[d * 16 + l16] = (bf16)(o_acc[s][d][r] * inv);
        }
}

// ---------------------------------------------------------------------------
extern "C" void kernel_launch(void* const* d_in, const int* in_sizes, int n_in,
                              void* d_out, int out_size, void* d_ws, size_t ws_size,
                              hipStream_t stream)
{
    const float* x          = (const float*)d_in[0];
    const float* ln1_w      = (const float*)d_in[1];
    const float* ln1_b      = (const float*)d_in[2];
    const float* w_qkv      = (const float*)d_in[3];
    const float* bias_table = (const float*)d_in[4];
    const float* w_out      = (const float*)d_in[5];
    const float* b_out      = (const float*)d_in[6];
    const float* ln2_w      = (const float*)d_in[7];
    const float* ln2_b      = (const float*)d_in[8];
    const float* w1         = (const float*)d_in[9];
    const float* b1         = (const float*)d_in[10];
    const float* w2         = (const float*)d_in[11];
    const float* b2         = (const float*)d_in[12];
    float* out = (float*)d_out;

    bf16* regA  = (bf16*)d_ws;                    // 25.17M elems: packs, later gelu
    bf16* Qpack = regA;                           // [128][1024][48]     6.29M
    bf16* Kpack = regA + 6291456;                 // [128][16][64][72]   9.44M
    bf16* Vpack = regA + 15728640;                // [128][16][64][72]   9.44M
    bf16* regB  = regA + (size_t)ROWS * HID;      // [16384][384]
    bf16* wqkvT = regB + (size_t)ROWS * D_MODEL;  // [1152][384]
    bf16* woutT = wqkvT + 1152 * 384;             // [384][384]
    bf16* w1T   = woutT + 384 * 384;              // [1536][384]
    bf16* w2T   = w1T + 1536 * 384;               // [384][1536]
    float* Btab = (float*)(w2T + 384 * 1536);     // [8][2016] f32 compressed
    float* x1   = out;                            // residual in d_out (f32)

    // 0. fused prep: wtrans x4 + pack_init + bias_prep + LN1
    prep_kernel<<<5176, 256, 0, stream>>>(
        w_qkv, w_out, w1, w2, wqkvT, woutT, w1T, w2T,
        Kpack, Vpack, bias_table, Btab, x, ln1_w, ln1_b, regB);
    // 2. qkv GEMM -> packed Q/K/V (EPI3)
    gemm3_kernel<3, bf16><<<(1152 / 128) * (ROWS / 128), 256, 0, stream>>>(
        regB, wqkvT, (bf16*)nullptr, nullptr, nullptr, 1152 / 128, 1152, D_MODEL,
        Qpack, Kpack, Vpack);
    // 3. attention -> regB  (512 blocks x 512 threads; 2 blocks/CU exactly)
    attn_kernel<<<512, 512, 0, stream>>>(Qpack, Kpack, Vpack, Btab, regB);
    // 4. x1 = attn @ w_out + b_out + x -> d_out (f32)
    gemm3_kernel<1, float><<<(D_MODEL / 128) * (ROWS / 128), 256, 0, stream>>>(
        regB, woutT, x1, b_out, x, D_MODEL / 128, D_MODEL, D_MODEL,
        nullptr, nullptr, nullptr);
    // 5. LN2 -> regB
    ln_kernel<<<ROWS / 4, 256, 0, stream>>>(x1, ln2_w, ln2_b, regB);
    // 6. gelu(h2 @ w1 + b1) -> regA (packs dead now)
    gemm3_kernel<2, bf16><<<(HID / 128) * (ROWS / 128), 256, 0, stream>>>(
        regB, w1T, regA, b1, nullptr, HID / 128, HID, D_MODEL,
        nullptr, nullptr, nullptr);
    // 7. out = gelu @ w2 + b2 + x1
    gemm3_kernel<1, float><<<(D_MODEL / 128) * (ROWS / 128), 256, 0, stream>>>(
        regA, w2T, out, b2, x1, D_MODEL / 128, D_MODEL, HID,
        nullptr, nullptr, nullptr);
}

// Round 9
// 294.931 us; speedup vs baseline: 1.0592x; 1.0103x over previous
//
#include <hip/hip_runtime.h>
#include <hip/hip_bf16.h>
#include <math.h>

typedef __bf16 bf16;
typedef __bf16 bf16x8 __attribute__((ext_vector_type(8)));
typedef __bf16 bf16x4 __attribute__((ext_vector_type(4)));
typedef __bf16 bf16x2 __attribute__((ext_vector_type(2)));
typedef float  f32x4  __attribute__((ext_vector_type(4)));
typedef int    i32x2  __attribute__((ext_vector_type(2)));

#define D_MODEL 384
#define HID     1536
#define NSEQ    1024
#define ROWS    16384
#define HEADS   8
#define DH      48
#define SCALE   0.14433756729740643f // 48^-0.5
#define MFIX    8.0f                 // fixed softmax max (scores bounded ~6.5)
// bias table compressed by dist(dy,dx)=dist(-dy,dx): [|dy| 0..31][dx+31 0..62]
#define BT2_N   2016                 // 32*63 entries per head, f32
// packed KV tile geometry: [64 rows][72 cols] bf16 = 9216 B per tile
#define KVT     4608                 // elems per tile
#define QP_BH   (NSEQ * DH)          // 49152 elems per bh in Qpack
#define KP_BH   (16 * KVT)           // 73728 elems per bh in K/Vpack

__device__ __forceinline__ void gload16(const void* g, void* l) {
    __builtin_amdgcn_global_load_lds((const __attribute__((address_space(1))) void*)g,
                                     (__attribute__((address_space(3))) void*)l, 16, 0, 0);
}

// tanh-form GELU: max |err| vs exact erf-GELU ~1e-3 (below bf16 quantization)
__device__ __forceinline__ float fast_gelu(float x) {
    float u = 0.7978845608f * fmaf(0.044715f * x * x, x, x);
    float e = __expf(2.f * u);
    float t = 1.f - 2.f * __builtin_amdgcn_rcpf(e + 1.f);   // tanh(u)
    return 0.5f * x * (1.f + t);
}

// ---------------------------------------------------------------------------
// Mega prep kernel: blockIdx-switched fusion of
//   [0,432)      wtrans x4 (w_qkv, w_out, w1, w2)
//   [432,1072)   pack_init (Kpack pad cols, Vpack ones-rows)
//   [1072,1080)  bias_prep (compressed |dy| table, f32, -MFIX folded)
//   [1080,5176)  LN1 (x -> regB bf16)
// ---------------------------------------------------------------------------
__device__ __forceinline__ void wtrans_body(const float* __restrict__ in,
                                            bf16* __restrict__ out, int K, int N,
                                            int bx, int by, float (*T)[65])
{
    const int k0 = by * 64, n0 = bx * 64;
    const int rr = threadIdx.x >> 4, rc = threadIdx.x & 15;
#pragma unroll
    for (int i = 0; i < 4; ++i) {
        float4 v = *(const float4*)(in + (size_t)(k0 + rr + i * 16) * N + n0 + rc * 4);
        T[rr + i * 16][rc * 4 + 0] = v.x;  T[rr + i * 16][rc * 4 + 1] = v.y;
        T[rr + i * 16][rc * 4 + 2] = v.z;  T[rr + i * 16][rc * 4 + 3] = v.w;
    }
    __syncthreads();
#pragma unroll
    for (int i = 0; i < 4; ++i) {
        int n = rr + i * 16, kc = rc * 4;
        bf16x4 o;
        o[0] = (bf16)T[kc + 0][n];  o[1] = (bf16)T[kc + 1][n];
        o[2] = (bf16)T[kc + 2][n];  o[3] = (bf16)T[kc + 3][n];
        *(bf16x4*)(out + (size_t)(n0 + n) * K + k0 + kc) = o;
    }
}

__device__ __forceinline__ void ln_body(const float* __restrict__ x,
                                        const float* __restrict__ w,
                                        const float* __restrict__ b,
                                        bf16* __restrict__ out, int blk)
{
    int row  = blk * 4 + ((int)threadIdx.x >> 6);
    int lane = threadIdx.x & 63;
    const float* xr = x + (size_t)row * D_MODEL;

    float2 v[3];
    float s = 0.f, ss = 0.f;
#pragma unroll
    for (int i = 0; i < 3; ++i) {
        v[i] = *(const float2*)(xr + lane * 2 + i * 128);
        s  += v[i].x + v[i].y;
        ss += v[i].x * v[i].x + v[i].y * v[i].y;
    }
#pragma unroll
    for (int off = 32; off; off >>= 1) {
        s  += __shfl_xor(s,  off);
        ss += __shfl_xor(ss, off);
    }
    float mu   = s * (1.f / D_MODEL);
    float var  = ss * (1.f / D_MODEL) - mu * mu;
    float rstd = rsqrtf(var + 1e-5f);

    bf16* orow = out + (size_t)row * D_MODEL;
#pragma unroll
    for (int i = 0; i < 3; ++i) {
        int c = lane * 2 + i * 128;
        float2 wv = *(const float2*)(w + c);
        float2 bv = *(const float2*)(b + c);
        bf16x2 o;
        o[0] = (bf16)((v[i].x - mu) * rstd * wv.x + bv.x);
        o[1] = (bf16)((v[i].y - mu) * rstd * wv.y + bv.y);
        *(bf16x2*)(orow + c) = o;
    }
}

__global__ __launch_bounds__(256)
void prep_kernel(const float* __restrict__ w_qkv, const float* __restrict__ w_out,
                 const float* __restrict__ w1, const float* __restrict__ w2,
                 bf16* __restrict__ wqkvT, bf16* __restrict__ woutT,
                 bf16* __restrict__ w1T, bf16* __restrict__ w2T,
                 bf16* __restrict__ Kp, bf16* __restrict__ Vp,
                 const float* __restrict__ bias_table, float* __restrict__ Btab,
                 const float* __restrict__ x, const float* __restrict__ ln1_w,
                 const float* __restrict__ ln1_b, bf16* __restrict__ regB)
{
    __shared__ float T[64][65];
    const int bid = blockIdx.x, tid = threadIdx.x;

    if (bid < 432) {                       // ---- weight transposes
        const float* in; bf16* outp; int K, N, nx, local;
        if (bid < 108)      { in = w_qkv; outp = wqkvT; K = 384;  N = 1152; local = bid;       nx = 18; }
        else if (bid < 144) { in = w_out; outp = woutT; K = 384;  N = 384;  local = bid - 108; nx = 6;  }
        else if (bid < 288) { in = w1;    outp = w1T;   K = 384;  N = 1536; local = bid - 144; nx = 24; }
        else                { in = w2;    outp = w2T;   K = 1536; N = 384;  local = bid - 288; nx = 6;  }
        wtrans_body(in, outp, K, N, local % nx, local / nx, T);
    } else if (bid < 1072) {               // ---- pack init
        const int pb = bid - 432;
        if (pb < 512) {                    // 131072 K-rows, pad cols 48..71
            int row = pb * 256 + tid;
            bf16x8 z = {};
            bf16* p = Kp + (size_t)row * 72 + 48;
            *(bf16x8*)(p) = z;  *(bf16x8*)(p + 8) = z;  *(bf16x8*)(p + 16) = z;
        } else {                           // 32768 V ones-rows
            int idx = (pb - 512) * 256 + tid;
            int tile = idx >> 4, rr = idx & 15;
            bf16 o = (bf16)1.f;
            bf16x8 ones = {o, o, o, o, o, o, o, o};
            bf16* p = Vp + (size_t)tile * KVT + (48 + rr) * 72;
#pragma unroll
            for (int c = 0; c < 9; ++c) *(bf16x8*)(p + c * 8) = ones;
        }
    } else if (bid < 1080) {               // ---- bias prep (compressed, f32)
        int idx = (bid - 1072) * 256 + tid;
        if (idx < BT2_N) {
            int dy = idx / 63, dx = idx % 63 - 31;
            int s2 = dy * dy + dx * dx;
            int r = (int)ceilf(sqrtf((float)s2));
            while (r * r < s2) ++r;
            while (r > 0 && (r - 1) * (r - 1) >= s2) --r;
#pragma unroll
            for (int h = 0; h < HEADS; ++h)
                Btab[h * BT2_N + idx] = bias_table[r * HEADS + h] - MFIX;
        }
    } else {                               // ---- LN1
        ln_body(x, ln1_w, ln1_b, regB, bid - 1080);
    }
}

// ---------------------------------------------------------------------------
// LayerNorm standalone (LN2): 4 rows per 256-thread block.
// ---------------------------------------------------------------------------
__global__ __launch_bounds__(256)
void ln_kernel(const float* __restrict__ x, const float* __restrict__ w,
               const float* __restrict__ b, bf16* __restrict__ out)
{
    ln_body(x, w, b, out, blockIdx.x);
}

// ---------------------------------------------------------------------------
// GEMM: C[M,N] = A[M,K] @ BT[N,K]^T, bf16, 128x128 tile, BK=64, XCD swizzle.
// v2 (verified r8): double-buffered LDS staging with counted vmcnt.
// EPI 1: +bias +f32 res -> f32.  EPI 2: +bias, fast GELU -> bf16.
// EPI 3: scatter to packed Q/K/V attn layouts (SCALE folded into Q).
// ---------------------------------------------------------------------------
template<int EPI, typename CT>
__global__ __launch_bounds__(256)
void gemm3_kernel(const bf16* __restrict__ A, const bf16* __restrict__ BT,
                  CT* __restrict__ C, const float* __restrict__ bias,
                  const float* __restrict__ res, int nxblk, int Nn, int K,
                  bf16* __restrict__ qp, bf16* __restrict__ kp, bf16* __restrict__ vp)
{
    __shared__ alignas(16) bf16 As[2][128][64];
    __shared__ alignas(16) bf16 Bs[2][128][64];

    const int bid  = blockIdx.x;
    const int xcd  = bid & 7;
    const int slot = bid >> 3;
    const int yy   = slot / nxblk;
    const int m0   = (yy * 8 + xcd) * 128;
    const int n0   = (slot - yy * nxblk) * 128;

    const int tid  = threadIdx.x;
    const int w    = tid >> 6;
    const int lane = tid & 63;
    const int quad = lane >> 4;
    const int l16  = lane & 15;

    const int srow = lane >> 3;          // 0..7
    const int scol = (lane & 7) * 8;     // 0..56

    f32x4 acc[4][4] = {};
    const int nst = K >> 6;

    // stage K-tile tt into buffer bufsel: every wave issues exactly 8 loads
    auto STAGE = [&](int tt, int bufsel) {
#pragma unroll
        for (int c = 0; c < 4; ++c) {
            const int ch = w * 4 + c;
            gload16(A  + (size_t)(m0 + ch * 8 + srow) * K + tt * 64 + scol,
                    &As[bufsel][ch * 8][0]);
            gload16(BT + (size_t)(n0 + ch * 8 + srow) * K + tt * 64 + scol,
                    &Bs[bufsel][ch * 8][0]);
        }
    };

    STAGE(0, 0);   // prologue

    for (int t = 0; t < nst; ++t) {
        const int cur = t & 1;
        if (t + 1 < nst) {
            STAGE(t + 1, cur ^ 1);
            asm volatile("s_waitcnt vmcnt(8)" ::: "memory");   // tile t landed
        } else {
            asm volatile("s_waitcnt vmcnt(0)" ::: "memory");
        }
        __builtin_amdgcn_s_barrier();            // all waves: buf[cur] ready
        __builtin_amdgcn_sched_barrier(0);

#pragma unroll
        for (int kk = 0; kk < 2; ++kk) {
            bf16x8 af[4], bfr[4];
#pragma unroll
            for (int mt = 0; mt < 4; ++mt)
                af[mt] = *(const bf16x8*)(&As[cur][(w & 1) * 64 + mt * 16 + l16][kk * 32 + quad * 8]);
#pragma unroll
            for (int nt = 0; nt < 4; ++nt)
                bfr[nt] = *(const bf16x8*)(&Bs[cur][(w >> 1) * 64 + nt * 16 + l16][kk * 32 + quad * 8]);
#pragma unroll
            for (int mt = 0; mt < 4; ++mt)
#pragma unroll
                for (int nt = 0; nt < 4; ++nt)
                    acc[mt][nt] = __builtin_amdgcn_mfma_f32_16x16x32_bf16(
                        af[mt], bfr[nt], acc[mt][nt], 0, 0, 0);
        }

        __builtin_amdgcn_s_barrier();   // protect buf[cur] from next STAGE
    }

#pragma unroll
    for (int mt = 0; mt < 4; ++mt) {
#pragma unroll
        for (int nt = 0; nt < 4; ++nt) {
            const int c0 = n0 + (w >> 1) * 64 + nt * 16;   // wave-uniform
            const int c  = c0 + l16;
            float bi = (EPI == 1 || EPI == 2) ? bias[c] : 0.f;
#pragma unroll
            for (int r = 0; r < 4; ++r) {
                int row = m0 + (w & 1) * 64 + mt * 16 + quad * 4 + r;
                float v = acc[mt][nt][r] + bi;
                if (EPI == 1) {
                    v += res[(size_t)row * Nn + c];
                    C[(size_t)row * Nn + c] = (CT)v;
                } else if (EPI == 2) {
                    v = fast_gelu(v);
                    C[(size_t)row * Nn + c] = (CT)v;
                } else { // EPI 3: packed QKV scatter
                    int b   = row >> 10, seq = row & 1023;
                    if (c0 < 384) {            // Q (scaled)
                        int h = c / 48, d = c - h * 48;
                        qp[(size_t)(b * 8 + h) * QP_BH + seq * 48 + d] = (bf16)(v * SCALE);
                    } else if (c0 < 768) {     // K
                        int ck = c - 384;
                        int h = ck / 48, d = ck - h * 48;
                        kp[(size_t)(b * 8 + h) * KP_BH + (seq >> 6) * KVT
                           + (seq & 63) * 72 + d] = (bf16)v;
                    } else {                   // V transposed
                        int cv = c - 768;
                        int h = cv / 48, d = cv - h * 48;
                        vp[(size_t)(b * 8 + h) * KP_BH + (seq >> 6) * KVT
                           + d * 72 + (seq & 63)] = (bf16)v;
                    }
                }
            }
        }
    }
}

// ---------------------------------------------------------------------------
// MFMA flash attention v10: v9 staging pipeline (double-buffered K/V,
// counted vmcnt, raw s_barrier) + ZERO-LDS softmax->PV handoff:
// QK^T C-layout (col=query l16, row=key quad*4+r) is EXACTLY the A-fragment
// layout of v_mfma_f32_16x16x16_bf16 (row=l16, k=quad*4+i), so exp'd scores
// feed PV straight from registers. B-frag = one ds_read_b64 of 4 contiguous
// keys at Vs[dblk*16+l16][...]; dblk=3 hits the ones-rows -> l-sum as before.
// Ps LDS buffer deleted (-8KB/wave/tile of LDS traffic).
// Inline asm for the 16x16x16 MFMA (ISA mnemonic); s_nop guards cover the
// VALU->MFMA SrcA/B and MFMA->VALU (epilogue) hazards the compiler no longer
// inserts for asm.
// LDS = 2*2*18432 + 8064 = 81792 B -> 2 blocks/CU.
// ---------------------------------------------------------------------------
__global__ __launch_bounds__(512)
void attn_kernel(const bf16* __restrict__ Qp, const bf16* __restrict__ Kp,
                 const bf16* __restrict__ Vp, const float* __restrict__ Btab,
                 bf16* __restrict__ out)
{
    __shared__ alignas(16) bf16 Ks[2][64][72];     // [buf][key][dh pad64]
    __shared__ alignas(16) bf16 Vs[2][64][72];     // [buf][dh][key]; rows 48..63 ones
    __shared__ alignas(16) float B2f[BT2_N];       // compressed bias, f32

    const int bid  = blockIdx.x;
    const int xcd  = bid & 7;
    const int slot = bid >> 3;                     // 0..63
    const int qc   = slot & 3;                     // 4 q-blocks of 256 rows
    const int bh   = (slot >> 2) * 8 + xcd;        // 0..127, all qc of bh on one XCD
    const int q0   = qc * 256;
    const int tid  = threadIdx.x;
    const int wave = tid >> 6;                     // 0..7
    const int lane = tid & 63;
    const int quad = lane >> 4;
    const int l16  = lane & 15;
    const int b    = bh >> 3, h = bh & 7;

    // stage compressed bias table (8064 B): one gload16 for threads 0..503
    {
        const char* src = (const char*)(Btab + (size_t)h * BT2_N);
        int off = tid * 16;
        if (off < BT2_N * 4)
            gload16(src + off, (char*)B2f + wave * 1024);
    }

    // Q fragments for 2 strips (B-operand), SCALE pre-applied in Qpack
    bf16x8 qf0[2], qf1[2];
    int qy[2], qxp[2];
#pragma unroll
    for (int s = 0; s < 2; ++s) {
        int qrow = q0 + s * 128 + wave * 16 + l16;
        const bf16* qptr = Qp + (size_t)bh * QP_BH + qrow * 48;
        qf0[s] = *(const bf16x8*)(qptr + quad * 8);
#pragma unroll
        for (int c = 0; c < 8; ++c) qf1[s][c] = (bf16)0.f;
        if (quad < 2) qf1[s] = *(const bf16x8*)(qptr + 32 + quad * 8);
        qy[s]  = qrow >> 5;
        qxp[s] = (qrow & 31) + 31;
    }

    f32x4 o_acc[2][4] = {};   // [strip][0..2 = O d-blocks, 3 = l]

    // async stage of tile tt into buffer bufsel: waves 0..5, 3 chunks each
    auto STAGE = [&](int tt, int bufsel) {
        if (wave < 6) {
            const bf16* kb = Kp + (size_t)(bh * 16 + tt) * KVT;
            const bf16* vb = Vp + (size_t)(bh * 16 + tt) * KVT;
#pragma unroll
            for (int j = 0; j < 3; ++j) {
                int i = wave * 3 + j;
                if (i < 9) gload16(kb + i * 512 + lane * 8,
                                   (bf16*)&Ks[bufsel][0][0] + i * 512);
                else       gload16(vb + (i - 9) * 512 + lane * 8,
                                   (bf16*)&Vs[bufsel][0][0] + (i - 9) * 512);
            }
        }
    };

    STAGE(0, 0);   // prologue

    for (int t = 0; t < 16; ++t) {
        const int cur = t & 1;
        if (t < 15) {
            STAGE(t + 1, cur ^ 1);
            asm volatile("s_waitcnt vmcnt(3)" ::: "memory");   // tile t landed
        } else {
            asm volatile("s_waitcnt vmcnt(0)" ::: "memory");
        }
        __builtin_amdgcn_s_barrier();            // all waves: buf[cur] ready
        __builtin_amdgcn_sched_barrier(0);

        const int n0 = t * 64;

        // S^T = K @ Q^T: D[key=quad*4+r][query=l16], K-frags shared by strips
        f32x4 sa[2][4] = {};
#pragma unroll
        for (int nt = 0; nt < 4; ++nt) {
            bf16x8 a0 = *(const bf16x8*)(&Ks[cur][nt * 16 + l16][quad * 8]);
            bf16x8 a1 = *(const bf16x8*)(&Ks[cur][nt * 16 + l16][32 + quad * 8]);
#pragma unroll
            for (int s = 0; s < 2; ++s) {
                sa[s][nt] = __builtin_amdgcn_mfma_f32_16x16x32_bf16(a0, qf0[s], sa[s][nt], 0, 0, 0);
                sa[s][nt] = __builtin_amdgcn_mfma_f32_16x16x32_bf16(a1, qf1[s], sa[s][nt], 0, 0, 0);
            }
        }

        // p = exp(s + bias - MFIX) -> PV A-fragments directly in registers
        bf16x4 pa[2][4];
#pragma unroll
        for (int s = 0; s < 2; ++s)
#pragma unroll
            for (int nt = 0; nt < 4; ++nt) {
                const int j0 = n0 + nt * 16 + quad * 4;
                int dy  = qy[s] - (j0 >> 5);
                int iay = dy < 0 ? -dy : dy;
                const int ib0 = iay * 63 + qxp[s] - (j0 & 31);
#pragma unroll
                for (int r = 0; r < 4; ++r)
                    pa[s][nt][r] = (bf16)__expf(sa[s][nt][r] + B2f[ib0 - r]);
            }

        // O += P @ V via 16x16x16 MFMA, P consumed in-register.
        // B-frag: Vs[dblk*16+l16][nt*16+quad*4 .. +3] (aligned ds_read_b64).
#pragma unroll
        for (int dblk = 0; dblk < 4; ++dblk) {
            i32x2 vb[4];
#pragma unroll
            for (int nt = 0; nt < 4; ++nt)
                vb[nt] = *(const i32x2*)(&Vs[cur][dblk * 16 + l16][nt * 16 + quad * 4]);
#pragma unroll
            for (int s = 0; s < 2; ++s)
#pragma unroll
                for (int nt = 0; nt < 4; ++nt) {
                    i32x2 pav = __builtin_bit_cast(i32x2, pa[s][nt]);
                    if (s == 0 && nt == 0)   // guard: VALU->MFMA SrcA/B hazard
                        asm("s_nop 1\n\tv_mfma_f32_16x16x16_bf16 %0, %1, %2, %0"
                            : "+v"(o_acc[s][dblk]) : "v"(pav), "v"(vb[nt]));
                    else
                        asm("v_mfma_f32_16x16x16_bf16 %0, %1, %2, %0"
                            : "+v"(o_acc[s][dblk]) : "v"(pav), "v"(vb[nt]));
                }
        }

        __builtin_amdgcn_s_barrier();   // protect buf[cur] from next STAGE
    }

    // drain MFMA->VALU hazard before reading o_acc (asm MFMAs get no
    // compiler-inserted waits)
    asm volatile("s_nop 7\n\ts_nop 7\n\ts_nop 7" :::);

    // epilogue
#pragma unroll
    for (int s = 0; s < 2; ++s)
#pragma unroll
        for (int r = 0; r < 4; ++r) {
            float inv = 1.f / o_acc[s][3][r];
            int row = q0 + s * 128 + wave * 16 + quad * 4 + r;
            bf16* orow = out + ((size_t)b * NSEQ + row) * D_MODEL + h * DH;
#pragma unroll
            for (int d = 0; d < 3; ++d)
                orow[d * 16 + l16] = (bf16)(o_acc[s][d][r] * inv);
        }
}

// ---------------------------------------------------------------------------
extern "C" void kernel_launch(void* const* d_in, const int* in_sizes, int n_in,
                              void* d_out, int out_size, void* d_ws, size_t ws_size,
                              hipStream_t stream)
{
    const float* x          = (const float*)d_in[0];
    const float* ln1_w      = (const float*)d_in[1];
    const float* ln1_b      = (const float*)d_in[2];
    const float* w_qkv      = (const float*)d_in[3];
    const float* bias_table = (const float*)d_in[4];
    const float* w_out      = (const float*)d_in[5];
    const float* b_out      = (const float*)d_in[6];
    const float* ln2_w      = (const float*)d_in[7];
    const float* ln2_b      = (const float*)d_in[8];
    const float* w1         = (const float*)d_in[9];
    const float* b1         = (const float*)d_in[10];
    const float* w2         = (const float*)d_in[11];
    const float* b2         = (const float*)d_in[12];
    float* out = (float*)d_out;

    bf16* regA  = (bf16*)d_ws;                    // 25.17M elems: packs, later gelu
    bf16* Qpack = regA;                           // [128][1024][48]     6.29M
    bf16* Kpack = regA + 6291456;                 // [128][16][64][72]   9.44M
    bf16* Vpack = regA + 15728640;                // [128][16][64][72]   9.44M
    bf16* regB  = regA + (size_t)ROWS * HID;      // [16384][384]
    bf16* wqkvT = regB + (size_t)ROWS * D_MODEL;  // [1152][384]
    bf16* woutT = wqkvT + 1152 * 384;             // [384][384]
    bf16* w1T   = woutT + 384 * 384;              // [1536][384]
    bf16* w2T   = w1T + 1536 * 384;               // [384][1536]
    float* Btab = (float*)(w2T + 384 * 1536);     // [8][2016] f32 compressed
    float* x1   = out;                            // residual in d_out (f32)

    // 0. fused prep: wtrans x4 + pack_init + bias_prep + LN1
    prep_kernel<<<5176, 256, 0, stream>>>(
        w_qkv, w_out, w1, w2, wqkvT, woutT, w1T, w2T,
        Kpack, Vpack, bias_table, Btab, x, ln1_w, ln1_b, regB);
    // 2. qkv GEMM -> packed Q/K/V (EPI3)
    gemm3_kernel<3, bf16><<<(1152 / 128) * (ROWS / 128), 256, 0, stream>>>(
        regB, wqkvT, (bf16*)nullptr, nullptr, nullptr, 1152 / 128, 1152, D_MODEL,
        Qpack, Kpack, Vpack);
    // 3. attention -> regB  (512 blocks x 512 threads; 2 blocks/CU exactly)
    attn_kernel<<<512, 512, 0, stream>>>(Qpack, Kpack, Vpack, Btab, regB);
    // 4. x1 = attn @ w_out + b_out + x -> d_out (f32)
    gemm3_kernel<1, float><<<(D_MODEL / 128) * (ROWS / 128), 256, 0, stream>>>(
        regB, woutT, x1, b_out, x, D_MODEL / 128, D_MODEL, D_MODEL,
        nullptr, nullptr, nullptr);
    // 5. LN2 -> regB
    ln_kernel<<<ROWS / 4, 256, 0, stream>>>(x1, ln2_w, ln2_b, regB);
    // 6. gelu(h2 @ w1 + b1) -> regA (packs dead now)
    gemm3_kernel<2, bf16><<<(HID / 128) * (ROWS / 128), 256, 0, stream>>>(
        regB, w1T, regA, b1, nullptr, HID / 128, HID, D_MODEL,
        nullptr, nullptr, nullptr);
    // 7. out = gelu @ w2 + b2 + x1
    gemm3_kernel<1, float><<<(D_MODEL / 128) * (ROWS / 128), 256, 0, stream>>>(
        regA, w2T, out, b2, x1, D_MODEL / 128, D_MODEL, HID,
        nullptr, nullptr, nullptr);
}

// Round 10
// 292.624 us; speedup vs baseline: 1.0675x; 1.0079x over previous
//
#include <hip/hip_runtime.h>
#include <hip/hip_bf16.h>
#include <math.h>

typedef __bf16 bf16;
typedef __bf16 bf16x8 __attribute__((ext_vector_type(8)));
typedef __bf16 bf16x4 __attribute__((ext_vector_type(4)));
typedef __bf16 bf16x2 __attribute__((ext_vector_type(2)));
typedef float  f32x4  __attribute__((ext_vector_type(4)));
typedef int    i32x2  __attribute__((ext_vector_type(2)));

#define D_MODEL 384
#define HID     1536
#define NSEQ    1024
#define ROWS    16384
#define HEADS   8
#define DH      48
#define SCALE   0.14433756729740643f // 48^-0.5
#define MFIX    8.0f                 // fixed softmax max (scores bounded ~6.5)
// bias table compressed by dist(dy,dx)=dist(-dy,dx): [|dy| 0..31][dx+31 0..62]
#define BT2_N   2016                 // 32*63 entries per head, f32
// packed KV tile geometry: [64 rows][72 cols] bf16 = 9216 B per tile
#define KVT     4608                 // elems per tile
#define QP_BH   (NSEQ * DH)          // 49152 elems per bh in Qpack
#define KP_BH   (16 * KVT)           // 73728 elems per bh in K/Vpack

__device__ __forceinline__ void gload16(const void* g, void* l) {
    __builtin_amdgcn_global_load_lds((const __attribute__((address_space(1))) void*)g,
                                     (__attribute__((address_space(3))) void*)l, 16, 0, 0);
}

// tanh-form GELU: max |err| vs exact erf-GELU ~1e-3 (below bf16 quantization)
__device__ __forceinline__ float fast_gelu(float x) {
    float u = 0.7978845608f * fmaf(0.044715f * x * x, x, x);
    float e = __expf(2.f * u);
    float t = 1.f - 2.f * __builtin_amdgcn_rcpf(e + 1.f);   // tanh(u)
    return 0.5f * x * (1.f + t);
}

// ---------------------------------------------------------------------------
// Mega prep kernel: blockIdx-switched fusion of
//   [0,432)      wtrans x4 (w_qkv, w_out, w1, w2)
//   [432,1072)   pack_init (Kpack pad cols, Vpack ones-rows)
//   [1072,1080)  bias_prep (compressed |dy| table, f32, -MFIX folded)
//   [1080,5176)  LN1 (x -> regB bf16)
// ---------------------------------------------------------------------------
__device__ __forceinline__ void wtrans_body(const float* __restrict__ in,
                                            bf16* __restrict__ out, int K, int N,
                                            int bx, int by, float (*T)[65])
{
    const int k0 = by * 64, n0 = bx * 64;
    const int rr = threadIdx.x >> 4, rc = threadIdx.x & 15;
#pragma unroll
    for (int i = 0; i < 4; ++i) {
        float4 v = *(const float4*)(in + (size_t)(k0 + rr + i * 16) * N + n0 + rc * 4);
        T[rr + i * 16][rc * 4 + 0] = v.x;  T[rr + i * 16][rc * 4 + 1] = v.y;
        T[rr + i * 16][rc * 4 + 2] = v.z;  T[rr + i * 16][rc * 4 + 3] = v.w;
    }
    __syncthreads();
#pragma unroll
    for (int i = 0; i < 4; ++i) {
        int n = rr + i * 16, kc = rc * 4;
        bf16x4 o;
        o[0] = (bf16)T[kc + 0][n];  o[1] = (bf16)T[kc + 1][n];
        o[2] = (bf16)T[kc + 2][n];  o[3] = (bf16)T[kc + 3][n];
        *(bf16x4*)(out + (size_t)(n0 + n) * K + k0 + kc) = o;
    }
}

__device__ __forceinline__ void ln_body(const float* __restrict__ x,
                                        const float* __restrict__ w,
                                        const float* __restrict__ b,
                                        bf16* __restrict__ out, int blk)
{
    int row  = blk * 4 + ((int)threadIdx.x >> 6);
    int lane = threadIdx.x & 63;
    const float* xr = x + (size_t)row * D_MODEL;

    float2 v[3];
    float s = 0.f, ss = 0.f;
#pragma unroll
    for (int i = 0; i < 3; ++i) {
        v[i] = *(const float2*)(xr + lane * 2 + i * 128);
        s  += v[i].x + v[i].y;
        ss += v[i].x * v[i].x + v[i].y * v[i].y;
    }
#pragma unroll
    for (int off = 32; off; off >>= 1) {
        s  += __shfl_xor(s,  off);
        ss += __shfl_xor(ss, off);
    }
    float mu   = s * (1.f / D_MODEL);
    float var  = ss * (1.f / D_MODEL) - mu * mu;
    float rstd = rsqrtf(var + 1e-5f);

    bf16* orow = out + (size_t)row * D_MODEL;
#pragma unroll
    for (int i = 0; i < 3; ++i) {
        int c = lane * 2 + i * 128;
        float2 wv = *(const float2*)(w + c);
        float2 bv = *(const float2*)(b + c);
        bf16x2 o;
        o[0] = (bf16)((v[i].x - mu) * rstd * wv.x + bv.x);
        o[1] = (bf16)((v[i].y - mu) * rstd * wv.y + bv.y);
        *(bf16x2*)(orow + c) = o;
    }
}

__global__ __launch_bounds__(256)
void prep_kernel(const float* __restrict__ w_qkv, const float* __restrict__ w_out,
                 const float* __restrict__ w1, const float* __restrict__ w2,
                 bf16* __restrict__ wqkvT, bf16* __restrict__ woutT,
                 bf16* __restrict__ w1T, bf16* __restrict__ w2T,
                 bf16* __restrict__ Kp, bf16* __restrict__ Vp,
                 const float* __restrict__ bias_table, float* __restrict__ Btab,
                 const float* __restrict__ x, const float* __restrict__ ln1_w,
                 const float* __restrict__ ln1_b, bf16* __restrict__ regB)
{
    __shared__ float T[64][65];
    const int bid = blockIdx.x, tid = threadIdx.x;

    if (bid < 432) {                       // ---- weight transposes
        const float* in; bf16* outp; int K, N, nx, local;
        if (bid < 108)      { in = w_qkv; outp = wqkvT; K = 384;  N = 1152; local = bid;       nx = 18; }
        else if (bid < 144) { in = w_out; outp = woutT; K = 384;  N = 384;  local = bid - 108; nx = 6;  }
        else if (bid < 288) { in = w1;    outp = w1T;   K = 384;  N = 1536; local = bid - 144; nx = 24; }
        else                { in = w2;    outp = w2T;   K = 1536; N = 384;  local = bid - 288; nx = 6;  }
        wtrans_body(in, outp, K, N, local % nx, local / nx, T);
    } else if (bid < 1072) {               // ---- pack init
        const int pb = bid - 432;
        if (pb < 512) {                    // 131072 K-rows, pad cols 48..71
            int row = pb * 256 + tid;
            bf16x8 z = {};
            bf16* p = Kp + (size_t)row * 72 + 48;
            *(bf16x8*)(p) = z;  *(bf16x8*)(p + 8) = z;  *(bf16x8*)(p + 16) = z;
        } else {                           // 32768 V ones-rows
            int idx = (pb - 512) * 256 + tid;
            int tile = idx >> 4, rr = idx & 15;
            bf16 o = (bf16)1.f;
            bf16x8 ones = {o, o, o, o, o, o, o, o};
            bf16* p = Vp + (size_t)tile * KVT + (48 + rr) * 72;
#pragma unroll
            for (int c = 0; c < 9; ++c) *(bf16x8*)(p + c * 8) = ones;
        }
    } else if (bid < 1080) {               // ---- bias prep (compressed, f32)
        int idx = (bid - 1072) * 256 + tid;
        if (idx < BT2_N) {
            int dy = idx / 63, dx = idx % 63 - 31;
            int s2 = dy * dy + dx * dx;
            int r = (int)ceilf(sqrtf((float)s2));
            while (r * r < s2) ++r;
            while (r > 0 && (r - 1) * (r - 1) >= s2) --r;
#pragma unroll
            for (int h = 0; h < HEADS; ++h)
                Btab[h * BT2_N + idx] = bias_table[r * HEADS + h] - MFIX;
        }
    } else {                               // ---- LN1
        ln_body(x, ln1_w, ln1_b, regB, bid - 1080);
    }
}

// ---------------------------------------------------------------------------
// LayerNorm standalone (LN2): 4 rows per 256-thread block.
// ---------------------------------------------------------------------------
__global__ __launch_bounds__(256)
void ln_kernel(const float* __restrict__ x, const float* __restrict__ w,
               const float* __restrict__ b, bf16* __restrict__ out)
{
    ln_body(x, w, b, out, blockIdx.x);
}

// ---------------------------------------------------------------------------
// GEMM: C[M,N] = A[M,K] @ BT[N,K]^T, bf16, 128x128 tile, XCD swizzle.
// v3: BK=32 double-buffered (LDS 32 KB -> 4-5 blocks/CU, 16-20 waves/CU)
// with counted vmcnt(4): tile t+1's 4 global_load_lds per wave issued before
// computing tile t; raw s_barrier, no vmcnt(0) drain in the K-loop.
// EPI 1: +bias +f32 res -> f32.  EPI 2: +bias, fast GELU -> bf16.
// EPI 3: scatter to packed Q/K/V attn layouts (SCALE folded into Q).
// ---------------------------------------------------------------------------
template<int EPI, typename CT>
__global__ __launch_bounds__(256)
void gemm3_kernel(const bf16* __restrict__ A, const bf16* __restrict__ BT,
                  CT* __restrict__ C, const float* __restrict__ bias,
                  const float* __restrict__ res, int nxblk, int Nn, int K,
                  bf16* __restrict__ qp, bf16* __restrict__ kp, bf16* __restrict__ vp)
{
    __shared__ alignas(16) bf16 As[2][128][32];
    __shared__ alignas(16) bf16 Bs[2][128][32];

    const int bid  = blockIdx.x;
    const int xcd  = bid & 7;
    const int slot = bid >> 3;
    const int yy   = slot / nxblk;
    const int m0   = (yy * 8 + xcd) * 128;
    const int n0   = (slot - yy * nxblk) * 128;

    const int tid  = threadIdx.x;
    const int w    = tid >> 6;
    const int lane = tid & 63;
    const int quad = lane >> 4;
    const int l16  = lane & 15;

    const int srow = lane >> 2;          // 0..15 (16 rows per 1KB chunk)
    const int scol = (lane & 3) * 8;     // 0..24

    f32x4 acc[4][4] = {};
    const int nst = K >> 5;

    // stage K-tile tt into buffer bufsel: every wave issues exactly 4 loads
    // (2 A-chunks + 2 B-chunks of 16 rows x 32 cols = 1KB each)
    auto STAGE = [&](int tt, int bufsel) {
#pragma unroll
        for (int j = 0; j < 2; ++j) {
            const int ch = w * 2 + j;    // 0..7
            gload16(A  + (size_t)(m0 + ch * 16 + srow) * K + tt * 32 + scol,
                    &As[bufsel][ch * 16][0]);
            gload16(BT + (size_t)(n0 + ch * 16 + srow) * K + tt * 32 + scol,
                    &Bs[bufsel][ch * 16][0]);
        }
    };

    STAGE(0, 0);   // prologue

    for (int t = 0; t < nst; ++t) {
        const int cur = t & 1;
        if (t + 1 < nst) {
            STAGE(t + 1, cur ^ 1);
            asm volatile("s_waitcnt vmcnt(4)" ::: "memory");   // tile t landed
        } else {
            asm volatile("s_waitcnt vmcnt(0)" ::: "memory");
        }
        __builtin_amdgcn_s_barrier();            // all waves: buf[cur] ready
        __builtin_amdgcn_sched_barrier(0);

        bf16x8 af[4], bfr[4];
#pragma unroll
        for (int mt = 0; mt < 4; ++mt)
            af[mt] = *(const bf16x8*)(&As[cur][(w & 1) * 64 + mt * 16 + l16][quad * 8]);
#pragma unroll
        for (int nt = 0; nt < 4; ++nt)
            bfr[nt] = *(const bf16x8*)(&Bs[cur][(w >> 1) * 64 + nt * 16 + l16][quad * 8]);
#pragma unroll
        for (int mt = 0; mt < 4; ++mt)
#pragma unroll
            for (int nt = 0; nt < 4; ++nt)
                acc[mt][nt] = __builtin_amdgcn_mfma_f32_16x16x32_bf16(
                    af[mt], bfr[nt], acc[mt][nt], 0, 0, 0);

        __builtin_amdgcn_s_barrier();   // protect buf[cur] from next STAGE
    }

#pragma unroll
    for (int mt = 0; mt < 4; ++mt) {
#pragma unroll
        for (int nt = 0; nt < 4; ++nt) {
            const int c0 = n0 + (w >> 1) * 64 + nt * 16;   // wave-uniform
            const int c  = c0 + l16;
            float bi = (EPI == 1 || EPI == 2) ? bias[c] : 0.f;
#pragma unroll
            for (int r = 0; r < 4; ++r) {
                int row = m0 + (w & 1) * 64 + mt * 16 + quad * 4 + r;
                float v = acc[mt][nt][r] + bi;
                if (EPI == 1) {
                    v += res[(size_t)row * Nn + c];
                    C[(size_t)row * Nn + c] = (CT)v;
                } else if (EPI == 2) {
                    v = fast_gelu(v);
                    C[(size_t)row * Nn + c] = (CT)v;
                } else { // EPI 3: packed QKV scatter
                    int b   = row >> 10, seq = row & 1023;
                    if (c0 < 384) {            // Q (scaled)
                        int h = c / 48, d = c - h * 48;
                        qp[(size_t)(b * 8 + h) * QP_BH + seq * 48 + d] = (bf16)(v * SCALE);
                    } else if (c0 < 768) {     // K
                        int ck = c - 384;
                        int h = ck / 48, d = ck - h * 48;
                        kp[(size_t)(b * 8 + h) * KP_BH + (seq >> 6) * KVT
                           + (seq & 63) * 72 + d] = (bf16)v;
                    } else {                   // V transposed
                        int cv = c - 768;
                        int h = cv / 48, d = cv - h * 48;
                        vp[(size_t)(b * 8 + h) * KP_BH + (seq >> 6) * KVT
                           + d * 72 + (seq & 63)] = (bf16)v;
                    }
                }
            }
        }
    }
}

// ---------------------------------------------------------------------------
// MFMA flash attention v10 (verified r9): double-buffered K/V with counted
// vmcnt + raw s_barrier; zero-LDS softmax->PV handoff via 16x16x16 MFMA
// (exp'd scores feed PV directly from registers; Ps buffer deleted).
// LDS = 2*2*18432 + 8064 = 81792 B -> 2 blocks/CU.
// ---------------------------------------------------------------------------
__global__ __launch_bounds__(512)
void attn_kernel(const bf16* __restrict__ Qp, const bf16* __restrict__ Kp,
                 const bf16* __restrict__ Vp, const float* __restrict__ Btab,
                 bf16* __restrict__ out)
{
    __shared__ alignas(16) bf16 Ks[2][64][72];     // [buf][key][dh pad64]
    __shared__ alignas(16) bf16 Vs[2][64][72];     // [buf][dh][key]; rows 48..63 ones
    __shared__ alignas(16) float B2f[BT2_N];       // compressed bias, f32

    const int bid  = blockIdx.x;
    const int xcd  = bid & 7;
    const int slot = bid >> 3;                     // 0..63
    const int qc   = slot & 3;                     // 4 q-blocks of 256 rows
    const int bh   = (slot >> 2) * 8 + xcd;        // 0..127, all qc of bh on one XCD
    const int q0   = qc * 256;
    const int tid  = threadIdx.x;
    const int wave = tid >> 6;                     // 0..7
    const int lane = tid & 63;
    const int quad = lane >> 4;
    const int l16  = lane & 15;
    const int b    = bh >> 3, h = bh & 7;

    // stage compressed bias table (8064 B): one gload16 for threads 0..503
    {
        const char* src = (const char*)(Btab + (size_t)h * BT2_N);
        int off = tid * 16;
        if (off < BT2_N * 4)
            gload16(src + off, (char*)B2f + wave * 1024);
    }

    // Q fragments for 2 strips (B-operand), SCALE pre-applied in Qpack
    bf16x8 qf0[2], qf1[2];
    int qy[2], qxp[2];
#pragma unroll
    for (int s = 0; s < 2; ++s) {
        int qrow = q0 + s * 128 + wave * 16 + l16;
        const bf16* qptr = Qp + (size_t)bh * QP_BH + qrow * 48;
        qf0[s] = *(const bf16x8*)(qptr + quad * 8);
#pragma unroll
        for (int c = 0; c < 8; ++c) qf1[s][c] = (bf16)0.f;
        if (quad < 2) qf1[s] = *(const bf16x8*)(qptr + 32 + quad * 8);
        qy[s]  = qrow >> 5;
        qxp[s] = (qrow & 31) + 31;
    }

    f32x4 o_acc[2][4] = {};   // [strip][0..2 = O d-blocks, 3 = l]

    // async stage of tile tt into buffer bufsel: waves 0..5, 3 chunks each
    auto STAGE = [&](int tt, int bufsel) {
        if (wave < 6) {
            const bf16* kb = Kp + (size_t)(bh * 16 + tt) * KVT;
            const bf16* vb = Vp + (size_t)(bh * 16 + tt) * KVT;
#pragma unroll
            for (int j = 0; j < 3; ++j) {
                int i = wave * 3 + j;
                if (i < 9) gload16(kb + i * 512 + lane * 8,
                                   (bf16*)&Ks[bufsel][0][0] + i * 512);
                else       gload16(vb + (i - 9) * 512 + lane * 8,
                                   (bf16*)&Vs[bufsel][0][0] + (i - 9) * 512);
            }
        }
    };

    STAGE(0, 0);   // prologue

    for (int t = 0; t < 16; ++t) {
        const int cur = t & 1;
        if (t < 15) {
            STAGE(t + 1, cur ^ 1);
            asm volatile("s_waitcnt vmcnt(3)" ::: "memory");   // tile t landed
        } else {
            asm volatile("s_waitcnt vmcnt(0)" ::: "memory");
        }
        __builtin_amdgcn_s_barrier();            // all waves: buf[cur] ready
        __builtin_amdgcn_sched_barrier(0);

        const int n0 = t * 64;

        // S^T = K @ Q^T: D[key=quad*4+r][query=l16], K-frags shared by strips
        f32x4 sa[2][4] = {};
#pragma unroll
        for (int nt = 0; nt < 4; ++nt) {
            bf16x8 a0 = *(const bf16x8*)(&Ks[cur][nt * 16 + l16][quad * 8]);
            bf16x8 a1 = *(const bf16x8*)(&Ks[cur][nt * 16 + l16][32 + quad * 8]);
#pragma unroll
            for (int s = 0; s < 2; ++s) {
                sa[s][nt] = __builtin_amdgcn_mfma_f32_16x16x32_bf16(a0, qf0[s], sa[s][nt], 0, 0, 0);
                sa[s][nt] = __builtin_amdgcn_mfma_f32_16x16x32_bf16(a1, qf1[s], sa[s][nt], 0, 0, 0);
            }
        }

        // p = exp(s + bias - MFIX) -> PV A-fragments directly in registers
        bf16x4 pa[2][4];
#pragma unroll
        for (int s = 0; s < 2; ++s)
#pragma unroll
            for (int nt = 0; nt < 4; ++nt) {
                const int j0 = n0 + nt * 16 + quad * 4;
                int dy  = qy[s] - (j0 >> 5);
                int iay = dy < 0 ? -dy : dy;
                const int ib0 = iay * 63 + qxp[s] - (j0 & 31);
#pragma unroll
                for (int r = 0; r < 4; ++r)
                    pa[s][nt][r] = (bf16)__expf(sa[s][nt][r] + B2f[ib0 - r]);
            }

        // O += P @ V via 16x16x16 MFMA, P consumed in-register.
        // B-frag: Vs[dblk*16+l16][nt*16+quad*4 .. +3] (aligned ds_read_b64).
#pragma unroll
        for (int dblk = 0; dblk < 4; ++dblk) {
            i32x2 vb[4];
#pragma unroll
            for (int nt = 0; nt < 4; ++nt)
                vb[nt] = *(const i32x2*)(&Vs[cur][dblk * 16 + l16][nt * 16 + quad * 4]);
#pragma unroll
            for (int s = 0; s < 2; ++s)
#pragma unroll
                for (int nt = 0; nt < 4; ++nt) {
                    i32x2 pav = __builtin_bit_cast(i32x2, pa[s][nt]);
                    if (s == 0 && nt == 0)   // guard: VALU->MFMA SrcA/B hazard
                        asm("s_nop 1\n\tv_mfma_f32_16x16x16_bf16 %0, %1, %2, %0"
                            : "+v"(o_acc[s][dblk]) : "v"(pav), "v"(vb[nt]));
                    else
                        asm("v_mfma_f32_16x16x16_bf16 %0, %1, %2, %0"
                            : "+v"(o_acc[s][dblk]) : "v"(pav), "v"(vb[nt]));
                }
        }

        __builtin_amdgcn_s_barrier();   // protect buf[cur] from next STAGE
    }

    // drain MFMA->VALU hazard before reading o_acc (asm MFMAs get no
    // compiler-inserted waits)
    asm volatile("s_nop 7\n\ts_nop 7\n\ts_nop 7" :::);

    // epilogue
#pragma unroll
    for (int s = 0; s < 2; ++s)
#pragma unroll
        for (int r = 0; r < 4; ++r) {
            float inv = 1.f / o_acc[s][3][r];
            int row = q0 + s * 128 + wave * 16 + quad * 4 + r;
            bf16* orow = out + ((size_t)b * NSEQ + row) * D_MODEL + h * DH;
#pragma unroll
            for (int d = 0; d < 3; ++d)
                orow[d * 16 + l16] = (bf16)(o_acc[s][d][r] * inv);
        }
}

// ---------------------------------------------------------------------------
extern "C" void kernel_launch(void* const* d_in, const int* in_sizes, int n_in,
                              void* d_out, int out_size, void* d_ws, size_t ws_size,
                              hipStream_t stream)
{
    const float* x          = (const float*)d_in[0];
    const float* ln1_w      = (const float*)d_in[1];
    const float* ln1_b      = (const float*)d_in[2];
    const float* w_qkv      = (const float*)d_in[3];
    const float* bias_table = (const float*)d_in[4];
    const float* w_out      = (const float*)d_in[5];
    const float* b_out      = (const float*)d_in[6];
    const float* ln2_w      = (const float*)d_in[7];
    const float* ln2_b      = (const float*)d_in[8];
    const float* w1         = (const float*)d_in[9];
    const float* b1         = (const float*)d_in[10];
    const float* w2         = (const float*)d_in[11];
    const float* b2         = (const float*)d_in[12];
    float* out = (float*)d_out;

    bf16* regA  = (bf16*)d_ws;                    // 25.17M elems: packs, later gelu
    bf16* Qpack = regA;                           // [128][1024][48]     6.29M
    bf16* Kpack = regA + 6291456;                 // [128][16][64][72]   9.44M
    bf16* Vpack = regA + 15728640;                // [128][16][64][72]   9.44M
    bf16* regB  = regA + (size_t)ROWS * HID;      // [16384][384]
    bf16* wqkvT = regB + (size_t)ROWS * D_MODEL;  // [1152][384]
    bf16* woutT = wqkvT + 1152 * 384;             // [384][384]
    bf16* w1T   = woutT + 384 * 384;              // [1536][384]
    bf16* w2T   = w1T + 1536 * 384;               // [384][1536]
    float* Btab = (float*)(w2T + 384 * 1536);     // [8][2016] f32 compressed
    float* x1   = out;                            // residual in d_out (f32)

    // 0. fused prep: wtrans x4 + pack_init + bias_prep + LN1
    prep_kernel<<<5176, 256, 0, stream>>>(
        w_qkv, w_out, w1, w2, wqkvT, woutT, w1T, w2T,
        Kpack, Vpack, bias_table, Btab, x, ln1_w, ln1_b, regB);
    // 2. qkv GEMM -> packed Q/K/V (EPI3)
    gemm3_kernel<3, bf16><<<(1152 / 128) * (ROWS / 128), 256, 0, stream>>>(
        regB, wqkvT, (bf16*)nullptr, nullptr, nullptr, 1152 / 128, 1152, D_MODEL,
        Qpack, Kpack, Vpack);
    // 3. attention -> regB  (512 blocks x 512 threads; 2 blocks/CU exactly)
    attn_kernel<<<512, 512, 0, stream>>>(Qpack, Kpack, Vpack, Btab, regB);
    // 4. x1 = attn @ w_out + b_out + x -> d_out (f32)
    gemm3_kernel<1, float><<<(D_MODEL / 128) * (ROWS / 128), 256, 0, stream>>>(
        regB, woutT, x1, b_out, x, D_MODEL / 128, D_MODEL, D_MODEL,
        nullptr, nullptr, nullptr);
    // 5. LN2 -> regB
    ln_kernel<<<ROWS / 4, 256, 0, stream>>>(x1, ln2_w, ln2_b, regB);
    // 6. gelu(h2 @ w1 + b1) -> regA (packs dead now)
    gemm3_kernel<2, bf16><<<(HID / 128) * (ROWS / 128), 256, 0, stream>>>(
        regB, w1T, regA, b1, nullptr, HID / 128, HID, D_MODEL,
        nullptr, nullptr, nullptr);
    // 7. out = gelu @ w2 + b2 + x1
    gemm3_kernel<1, float><<<(D_MODEL / 128) * (ROWS / 128), 256, 0, stream>>>(
        regA, w2T, out, b2, x1, D_MODEL / 128, D_MODEL, HID,
        nullptr, nullptr, nullptr);
}

// Round 11
// 266.596 us; speedup vs baseline: 1.1718x; 1.0976x over previous
//
#include <hip/hip_runtime.h>
#include <hip/hip_bf16.h>
#include <math.h>

typedef __bf16 bf16;
typedef __bf16 bf16x8 __attribute__((ext_vector_type(8)));
typedef __bf16 bf16x4 __attribute__((ext_vector_type(4)));
typedef __bf16 bf16x2 __attribute__((ext_vector_type(2)));
typedef float  f32x4  __attribute__((ext_vector_type(4)));
typedef int    i32x2  __attribute__((ext_vector_type(2)));

#define D_MODEL 384
#define HID     1536
#define NSEQ    1024
#define ROWS    16384
#define HEADS   8
#define DH      48
#define SCALE   0.14433756729740643f // 48^-0.5
#define MFIX    8.0f                 // fixed softmax max (scores bounded ~6.5)
// bias table compressed by dist(dy,dx)=dist(-dy,dx): [|dy| 0..31][dx+31 0..62]
#define BT2_N   2016                 // 32*63 entries per head, f32
// packed KV tile geometry: [64 rows][72 cols] bf16 = 9216 B per tile
#define KVT     4608                 // elems per tile
#define QP_BH   (NSEQ * DH)          // 49152 elems per bh in Qpack
#define KP_BH   (16 * KVT)           // 73728 elems per bh in K/Vpack

__device__ __forceinline__ void gload16(const void* g, void* l) {
    __builtin_amdgcn_global_load_lds((const __attribute__((address_space(1))) void*)g,
                                     (__attribute__((address_space(3))) void*)l, 16, 0, 0);
}

// tanh-form GELU: max |err| vs exact erf-GELU ~1e-3 (below bf16 quantization)
__device__ __forceinline__ float fast_gelu(float x) {
    float u = 0.7978845608f * fmaf(0.044715f * x * x, x, x);
    float e = __expf(2.f * u);
    float t = 1.f - 2.f * __builtin_amdgcn_rcpf(e + 1.f);   // tanh(u)
    return 0.5f * x * (1.f + t);
}

// ---------------------------------------------------------------------------
// Mega prep kernel: blockIdx-switched fusion of
//   [0,432)      wtrans x4 (w_qkv, w_out, w1, w2)
//   [432,1072)   pack_init (Kpack pad cols, Vpack ones-rows)
//   [1072,1080)  bias_prep (compressed |dy| table, f32, -MFIX folded)
//   [1080,5176)  LN1 (x -> regB bf16)
// ---------------------------------------------------------------------------
__device__ __forceinline__ void wtrans_body(const float* __restrict__ in,
                                            bf16* __restrict__ out, int K, int N,
                                            int bx, int by, float (*T)[65])
{
    const int k0 = by * 64, n0 = bx * 64;
    const int rr = threadIdx.x >> 4, rc = threadIdx.x & 15;
#pragma unroll
    for (int i = 0; i < 4; ++i) {
        float4 v = *(const float4*)(in + (size_t)(k0 + rr + i * 16) * N + n0 + rc * 4);
        T[rr + i * 16][rc * 4 + 0] = v.x;  T[rr + i * 16][rc * 4 + 1] = v.y;
        T[rr + i * 16][rc * 4 + 2] = v.z;  T[rr + i * 16][rc * 4 + 3] = v.w;
    }
    __syncthreads();
#pragma unroll
    for (int i = 0; i < 4; ++i) {
        int n = rr + i * 16, kc = rc * 4;
        bf16x4 o;
        o[0] = (bf16)T[kc + 0][n];  o[1] = (bf16)T[kc + 1][n];
        o[2] = (bf16)T[kc + 2][n];  o[3] = (bf16)T[kc + 3][n];
        *(bf16x4*)(out + (size_t)(n0 + n) * K + k0 + kc) = o;
    }
}

__device__ __forceinline__ void ln_body(const float* __restrict__ x,
                                        const float* __restrict__ w,
                                        const float* __restrict__ b,
                                        bf16* __restrict__ out, int blk)
{
    int row  = blk * 4 + ((int)threadIdx.x >> 6);
    int lane = threadIdx.x & 63;
    const float* xr = x + (size_t)row * D_MODEL;

    float2 v[3];
    float s = 0.f, ss = 0.f;
#pragma unroll
    for (int i = 0; i < 3; ++i) {
        v[i] = *(const float2*)(xr + lane * 2 + i * 128);
        s  += v[i].x + v[i].y;
        ss += v[i].x * v[i].x + v[i].y * v[i].y;
    }
#pragma unroll
    for (int off = 32; off; off >>= 1) {
        s  += __shfl_xor(s,  off);
        ss += __shfl_xor(ss, off);
    }
    float mu   = s * (1.f / D_MODEL);
    float var  = ss * (1.f / D_MODEL) - mu * mu;
    float rstd = rsqrtf(var + 1e-5f);

    bf16* orow = out + (size_t)row * D_MODEL;
#pragma unroll
    for (int i = 0; i < 3; ++i) {
        int c = lane * 2 + i * 128;
        float2 wv = *(const float2*)(w + c);
        float2 bv = *(const float2*)(b + c);
        bf16x2 o;
        o[0] = (bf16)((v[i].x - mu) * rstd * wv.x + bv.x);
        o[1] = (bf16)((v[i].y - mu) * rstd * wv.y + bv.y);
        *(bf16x2*)(orow + c) = o;
    }
}

__global__ __launch_bounds__(256)
void prep_kernel(const float* __restrict__ w_qkv, const float* __restrict__ w_out,
                 const float* __restrict__ w1, const float* __restrict__ w2,
                 bf16* __restrict__ wqkvT, bf16* __restrict__ woutT,
                 bf16* __restrict__ w1T, bf16* __restrict__ w2T,
                 bf16* __restrict__ Kp, bf16* __restrict__ Vp,
                 const float* __restrict__ bias_table, float* __restrict__ Btab,
                 const float* __restrict__ x, const float* __restrict__ ln1_w,
                 const float* __restrict__ ln1_b, bf16* __restrict__ regB)
{
    __shared__ float T[64][65];
    const int bid = blockIdx.x, tid = threadIdx.x;

    if (bid < 432) {                       // ---- weight transposes
        const float* in; bf16* outp; int K, N, nx, local;
        if (bid < 108)      { in = w_qkv; outp = wqkvT; K = 384;  N = 1152; local = bid;       nx = 18; }
        else if (bid < 144) { in = w_out; outp = woutT; K = 384;  N = 384;  local = bid - 108; nx = 6;  }
        else if (bid < 288) { in = w1;    outp = w1T;   K = 384;  N = 1536; local = bid - 144; nx = 24; }
        else                { in = w2;    outp = w2T;   K = 1536; N = 384;  local = bid - 288; nx = 6;  }
        wtrans_body(in, outp, K, N, local % nx, local / nx, T);
    } else if (bid < 1072) {               // ---- pack init
        const int pb = bid - 432;
        if (pb < 512) {                    // 131072 K-rows, pad cols 48..71
            int row = pb * 256 + tid;
            bf16x8 z = {};
            bf16* p = Kp + (size_t)row * 72 + 48;
            *(bf16x8*)(p) = z;  *(bf16x8*)(p + 8) = z;  *(bf16x8*)(p + 16) = z;
        } else {                           // 32768 V ones-rows
            int idx = (pb - 512) * 256 + tid;
            int tile = idx >> 4, rr = idx & 15;
            bf16 o = (bf16)1.f;
            bf16x8 ones = {o, o, o, o, o, o, o, o};
            bf16* p = Vp + (size_t)tile * KVT + (48 + rr) * 72;
#pragma unroll
            for (int c = 0; c < 9; ++c) *(bf16x8*)(p + c * 8) = ones;
        }
    } else if (bid < 1080) {               // ---- bias prep (compressed, f32)
        int idx = (bid - 1072) * 256 + tid;
        if (idx < BT2_N) {
            int dy = idx / 63, dx = idx % 63 - 31;
            int s2 = dy * dy + dx * dx;
            int r = (int)ceilf(sqrtf((float)s2));
            while (r * r < s2) ++r;
            while (r > 0 && (r - 1) * (r - 1) >= s2) --r;
#pragma unroll
            for (int h = 0; h < HEADS; ++h)
                Btab[h * BT2_N + idx] = bias_table[r * HEADS + h] - MFIX;
        }
    } else {                               // ---- LN1
        ln_body(x, ln1_w, ln1_b, regB, bid - 1080);
    }
}

// ---------------------------------------------------------------------------
// LayerNorm standalone (LN2): 4 rows per 256-thread block.
// ---------------------------------------------------------------------------
__global__ __launch_bounds__(256)
void ln_kernel(const float* __restrict__ x, const float* __restrict__ w,
               const float* __restrict__ b, bf16* __restrict__ out)
{
    ln_body(x, w, b, out, blockIdx.x);
}

// ---------------------------------------------------------------------------
// GEMM: C[M,N] = A[M,K] @ BT[N,K]^T, bf16, 128x128 tile, XCD swizzle.
// v4: BK=32 double-buffered, counted vmcnt(4), raw s_barrier (verified r10).
// EPI 1: +bias +f32 res -> f32.  EPI 2: +bias, fast GELU -> bf16.
// EPI 3: packed QKV. Q/K scatter as before (32B-granule). V blocks
// (n0>=768, block-uniform) now do an IN-LDS TRANSPOSE + 16B coalesced
// stores instead of 2B stride-144 scatter (was ~6.3M isolated sector
// writes). LDS scratch Vt[128][136] aliases As/Bs via manual carve
// (safe: used only after the K-loop, behind a barrier). LDS 34816 B.
// ---------------------------------------------------------------------------
template<int EPI, typename CT>
__global__ __launch_bounds__(256)
void gemm3_kernel(const bf16* __restrict__ A, const bf16* __restrict__ BT,
                  CT* __restrict__ C, const float* __restrict__ bias,
                  const float* __restrict__ res, int nxblk, int Nn, int K,
                  bf16* __restrict__ qp, bf16* __restrict__ kp, bf16* __restrict__ vp)
{
    __shared__ alignas(16) char smem[34816];
    typedef bf16 TileT[128][32];
    TileT* As = (TileT*)smem;                      // As[0..1]: 16384 B
    TileT* Bs = (TileT*)(smem + 16384);            // Bs[0..1]: 16384 B
    typedef bf16 VtRow[136];
    VtRow* Vt = (VtRow*)smem;                      // [128][136] aliased, 34816 B

    const int bid  = blockIdx.x;
    const int xcd  = bid & 7;
    const int slot = bid >> 3;
    const int yy   = slot / nxblk;
    const int m0   = (yy * 8 + xcd) * 128;
    const int n0   = (slot - yy * nxblk) * 128;

    const int tid  = threadIdx.x;
    const int w    = tid >> 6;
    const int lane = tid & 63;
    const int quad = lane >> 4;
    const int l16  = lane & 15;

    const int srow = lane >> 2;          // 0..15 (16 rows per 1KB chunk)
    const int scol = (lane & 3) * 8;     // 0..24

    f32x4 acc[4][4] = {};
    const int nst = K >> 5;

    // stage K-tile tt into buffer bufsel: every wave issues exactly 4 loads
    auto STAGE = [&](int tt, int bufsel) {
#pragma unroll
        for (int j = 0; j < 2; ++j) {
            const int ch = w * 2 + j;    // 0..7
            gload16(A  + (size_t)(m0 + ch * 16 + srow) * K + tt * 32 + scol,
                    &As[bufsel][ch * 16][0]);
            gload16(BT + (size_t)(n0 + ch * 16 + srow) * K + tt * 32 + scol,
                    &Bs[bufsel][ch * 16][0]);
        }
    };

    STAGE(0, 0);   // prologue

    for (int t = 0; t < nst; ++t) {
        const int cur = t & 1;
        if (t + 1 < nst) {
            STAGE(t + 1, cur ^ 1);
            asm volatile("s_waitcnt vmcnt(4)" ::: "memory");   // tile t landed
        } else {
            asm volatile("s_waitcnt vmcnt(0)" ::: "memory");
        }
        __builtin_amdgcn_s_barrier();            // all waves: buf[cur] ready
        __builtin_amdgcn_sched_barrier(0);

        bf16x8 af[4], bfr[4];
#pragma unroll
        for (int mt = 0; mt < 4; ++mt)
            af[mt] = *(const bf16x8*)(&As[cur][(w & 1) * 64 + mt * 16 + l16][quad * 8]);
#pragma unroll
        for (int nt = 0; nt < 4; ++nt)
            bfr[nt] = *(const bf16x8*)(&Bs[cur][(w >> 1) * 64 + nt * 16 + l16][quad * 8]);
#pragma unroll
        for (int mt = 0; mt < 4; ++mt)
#pragma unroll
            for (int nt = 0; nt < 4; ++nt)
                acc[mt][nt] = __builtin_amdgcn_mfma_f32_16x16x32_bf16(
                    af[mt], bfr[nt], acc[mt][nt], 0, 0, 0);

        __builtin_amdgcn_s_barrier();   // protect buf[cur] from next STAGE
    }

    if (EPI == 3 && n0 >= 768) {
        // ---- V panel: in-LDS transpose -> coalesced 16B stores ----
        __syncthreads();               // all waves done with As/Bs LDS reads
#pragma unroll
        for (int mt = 0; mt < 4; ++mt)
#pragma unroll
            for (int nt = 0; nt < 4; ++nt) {
                const int cl = (w >> 1) * 64 + nt * 16 + l16;
#pragma unroll
                for (int r = 0; r < 4; ++r) {
                    const int rl = (w & 1) * 64 + mt * 16 + quad * 4 + r;
                    Vt[cl][rl] = (bf16)acc[mt][nt][r];
                }
            }
        __syncthreads();
        const int bb = m0 >> 10, seq0 = m0 & 1023;
#pragma unroll
        for (int it = 0; it < 8; ++it) {
            const int ch  = it * 256 + tid;       // 0..2047
            const int col = ch >> 4, seg = ch & 15;
            const int cv  = n0 - 768 + col;
            const int hh  = cv / 48, dd = cv - hh * 48;
            const int sq  = seq0 + seg * 8;
            bf16x8 val = *(const bf16x8*)(&Vt[col][seg * 8]);
            *(bf16x8*)(&vp[(size_t)(bb * 8 + hh) * KP_BH + (sq >> 6) * KVT
                           + dd * 72 + (sq & 63)]) = val;
        }
        return;
    }

#pragma unroll
    for (int mt = 0; mt < 4; ++mt) {
#pragma unroll
        for (int nt = 0; nt < 4; ++nt) {
            const int c0 = n0 + (w >> 1) * 64 + nt * 16;   // wave-uniform
            const int c  = c0 + l16;
            float bi = (EPI == 1 || EPI == 2) ? bias[c] : 0.f;
#pragma unroll
            for (int r = 0; r < 4; ++r) {
                int row = m0 + (w & 1) * 64 + mt * 16 + quad * 4 + r;
                float v = acc[mt][nt][r] + bi;
                if (EPI == 1) {
                    v += res[(size_t)row * Nn + c];
                    C[(size_t)row * Nn + c] = (CT)v;
                } else if (EPI == 2) {
                    v = fast_gelu(v);
                    C[(size_t)row * Nn + c] = (CT)v;
                } else { // EPI 3: Q/K panels (n0 < 768)
                    int b   = row >> 10, seq = row & 1023;
                    if (c0 < 384) {            // Q (scaled)
                        int h = c / 48, d = c - h * 48;
                        qp[(size_t)(b * 8 + h) * QP_BH + seq * 48 + d] = (bf16)(v * SCALE);
                    } else {                   // K
                        int ck = c - 384;
                        int h = ck / 48, d = ck - h * 48;
                        kp[(size_t)(b * 8 + h) * KP_BH + (seq >> 6) * KVT
                           + (seq & 63) * 72 + d] = (bf16)v;
                    }
                }
            }
        }
    }
}

// ---------------------------------------------------------------------------
// MFMA flash attention v10 (verified r9/r10): double-buffered K/V with
// counted vmcnt + raw s_barrier; zero-LDS softmax->PV handoff via 16x16x16
// MFMA (exp'd scores feed PV directly from registers).
// LDS = 2*2*18432 + 8064 = 81792 B -> 2 blocks/CU.
// ---------------------------------------------------------------------------
__global__ __launch_bounds__(512)
void attn_kernel(const bf16* __restrict__ Qp, const bf16* __restrict__ Kp,
                 const bf16* __restrict__ Vp, const float* __restrict__ Btab,
                 bf16* __restrict__ out)
{
    __shared__ alignas(16) bf16 Ks[2][64][72];     // [buf][key][dh pad64]
    __shared__ alignas(16) bf16 Vs[2][64][72];     // [buf][dh][key]; rows 48..63 ones
    __shared__ alignas(16) float B2f[BT2_N];       // compressed bias, f32

    const int bid  = blockIdx.x;
    const int xcd  = bid & 7;
    const int slot = bid >> 3;                     // 0..63
    const int qc   = slot & 3;                     // 4 q-blocks of 256 rows
    const int bh   = (slot >> 2) * 8 + xcd;        // 0..127, all qc of bh on one XCD
    const int q0   = qc * 256;
    const int tid  = threadIdx.x;
    const int wave = tid >> 6;                     // 0..7
    const int lane = tid & 63;
    const int quad = lane >> 4;
    const int l16  = lane & 15;
    const int b    = bh >> 3, h = bh & 7;

    // stage compressed bias table (8064 B): one gload16 for threads 0..503
    {
        const char* src = (const char*)(Btab + (size_t)h * BT2_N);
        int off = tid * 16;
        if (off < BT2_N * 4)
            gload16(src + off, (char*)B2f + wave * 1024);
    }

    // Q fragments for 2 strips (B-operand), SCALE pre-applied in Qpack
    bf16x8 qf0[2], qf1[2];
    int qy[2], qxp[2];
#pragma unroll
    for (int s = 0; s < 2; ++s) {
        int qrow = q0 + s * 128 + wave * 16 + l16;
        const bf16* qptr = Qp + (size_t)bh * QP_BH + qrow * 48;
        qf0[s] = *(const bf16x8*)(qptr + quad * 8);
#pragma unroll
        for (int c = 0; c < 8; ++c) qf1[s][c] = (bf16)0.f;
        if (quad < 2) qf1[s] = *(const bf16x8*)(qptr + 32 + quad * 8);
        qy[s]  = qrow >> 5;
        qxp[s] = (qrow & 31) + 31;
    }

    f32x4 o_acc[2][4] = {};   // [strip][0..2 = O d-blocks, 3 = l]

    // async stage of tile tt into buffer bufsel: waves 0..5, 3 chunks each
    auto STAGE = [&](int tt, int bufsel) {
        if (wave < 6) {
            const bf16* kb = Kp + (size_t)(bh * 16 + tt) * KVT;
            const bf16* vb = Vp + (size_t)(bh * 16 + tt) * KVT;
#pragma unroll
            for (int j = 0; j < 3; ++j) {
                int i = wave * 3 + j;
                if (i < 9) gload16(kb + i * 512 + lane * 8,
                                   (bf16*)&Ks[bufsel][0][0] + i * 512);
                else       gload16(vb + (i - 9) * 512 + lane * 8,
                                   (bf16*)&Vs[bufsel][0][0] + (i - 9) * 512);
            }
        }
    };

    STAGE(0, 0);   // prologue

    for (int t = 0; t < 16; ++t) {
        const int cur = t & 1;
        if (t < 15) {
            STAGE(t + 1, cur ^ 1);
            asm volatile("s_waitcnt vmcnt(3)" ::: "memory");   // tile t landed
        } else {
            asm volatile("s_waitcnt vmcnt(0)" ::: "memory");
        }
        __builtin_amdgcn_s_barrier();            // all waves: buf[cur] ready
        __builtin_amdgcn_sched_barrier(0);

        const int n0 = t * 64;

        // S^T = K @ Q^T: D[key=quad*4+r][query=l16], K-frags shared by strips
        f32x4 sa[2][4] = {};
#pragma unroll
        for (int nt = 0; nt < 4; ++nt) {
            bf16x8 a0 = *(const bf16x8*)(&Ks[cur][nt * 16 + l16][quad * 8]);
            bf16x8 a1 = *(const bf16x8*)(&Ks[cur][nt * 16 + l16][32 + quad * 8]);
#pragma unroll
            for (int s = 0; s < 2; ++s) {
                sa[s][nt] = __builtin_amdgcn_mfma_f32_16x16x32_bf16(a0, qf0[s], sa[s][nt], 0, 0, 0);
                sa[s][nt] = __builtin_amdgcn_mfma_f32_16x16x32_bf16(a1, qf1[s], sa[s][nt], 0, 0, 0);
            }
        }

        // p = exp(s + bias - MFIX) -> PV A-fragments directly in registers
        bf16x4 pa[2][4];
#pragma unroll
        for (int s = 0; s < 2; ++s)
#pragma unroll
            for (int nt = 0; nt < 4; ++nt) {
                const int j0 = n0 + nt * 16 + quad * 4;
                int dy  = qy[s] - (j0 >> 5);
                int iay = dy < 0 ? -dy : dy;
                const int ib0 = iay * 63 + qxp[s] - (j0 & 31);
#pragma unroll
                for (int r = 0; r < 4; ++r)
                    pa[s][nt][r] = (bf16)__expf(sa[s][nt][r] + B2f[ib0 - r]);
            }

        // O += P @ V via 16x16x16 MFMA, P consumed in-register.
        // B-frag: Vs[dblk*16+l16][nt*16+quad*4 .. +3] (aligned ds_read_b64).
#pragma unroll
        for (int dblk = 0; dblk < 4; ++dblk) {
            i32x2 vb[4];
#pragma unroll
            for (int nt = 0; nt < 4; ++nt)
                vb[nt] = *(const i32x2*)(&Vs[cur][dblk * 16 + l16][nt * 16 + quad * 4]);
#pragma unroll
            for (int s = 0; s < 2; ++s)
#pragma unroll
                for (int nt = 0; nt < 4; ++nt) {
                    i32x2 pav = __builtin_bit_cast(i32x2, pa[s][nt]);
                    if (s == 0 && nt == 0)   // guard: VALU->MFMA SrcA/B hazard
                        asm("s_nop 1\n\tv_mfma_f32_16x16x16_bf16 %0, %1, %2, %0"
                            : "+v"(o_acc[s][dblk]) : "v"(pav), "v"(vb[nt]));
                    else
                        asm("v_mfma_f32_16x16x16_bf16 %0, %1, %2, %0"
                            : "+v"(o_acc[s][dblk]) : "v"(pav), "v"(vb[nt]));
                }
        }

        __builtin_amdgcn_s_barrier();   // protect buf[cur] from next STAGE
    }

    // drain MFMA->VALU hazard before reading o_acc (asm MFMAs get no
    // compiler-inserted waits)
    asm volatile("s_nop 7\n\ts_nop 7\n\ts_nop 7" :::);

    // epilogue
#pragma unroll
    for (int s = 0; s < 2; ++s)
#pragma unroll
        for (int r = 0; r < 4; ++r) {
            float inv = 1.f / o_acc[s][3][r];
            int row = q0 + s * 128 + wave * 16 + quad * 4 + r;
            bf16* orow = out + ((size_t)b * NSEQ + row) * D_MODEL + h * DH;
#pragma unroll
            for (int d = 0; d < 3; ++d)
                orow[d * 16 + l16] = (bf16)(o_acc[s][d][r] * inv);
        }
}

// ---------------------------------------------------------------------------
extern "C" void kernel_launch(void* const* d_in, const int* in_sizes, int n_in,
                              void* d_out, int out_size, void* d_ws, size_t ws_size,
                              hipStream_t stream)
{
    const float* x          = (const float*)d_in[0];
    const float* ln1_w      = (const float*)d_in[1];
    const float* ln1_b      = (const float*)d_in[2];
    const float* w_qkv      = (const float*)d_in[3];
    const float* bias_table = (const float*)d_in[4];
    const float* w_out      = (const float*)d_in[5];
    const float* b_out      = (const float*)d_in[6];
    const float* ln2_w      = (const float*)d_in[7];
    const float* ln2_b      = (const float*)d_in[8];
    const float* w1         = (const float*)d_in[9];
    const float* b1         = (const float*)d_in[10];
    const float* w2         = (const float*)d_in[11];
    const float* b2         = (const float*)d_in[12];
    float* out = (float*)d_out;

    bf16* regA  = (bf16*)d_ws;                    // 25.17M elems: packs, later gelu
    bf16* Qpack = regA;                           // [128][1024][48]     6.29M
    bf16* Kpack = regA + 6291456;                 // [128][16][64][72]   9.44M
    bf16* Vpack = regA + 15728640;                // [128][16][64][72]   9.44M
    bf16* regB  = regA + (size_t)ROWS * HID;      // [16384][384]
    bf16* wqkvT = regB + (size_t)ROWS * D_MODEL;  // [1152][384]
    bf16* woutT = wqkvT + 1152 * 384;             // [384][384]
    bf16* w1T   = woutT + 384 * 384;              // [1536][384]
    bf16* w2T   = w1T + 1536 * 384;               // [384][1536]
    float* Btab = (float*)(w2T + 384 * 1536);     // [8][2016] f32 compressed
    float* x1   = out;                            // residual in d_out (f32)

    // 0. fused prep: wtrans x4 + pack_init + bias_prep + LN1
    prep_kernel<<<5176, 256, 0, stream>>>(
        w_qkv, w_out, w1, w2, wqkvT, woutT, w1T, w2T,
        Kpack, Vpack, bias_table, Btab, x, ln1_w, ln1_b, regB);
    // 2. qkv GEMM -> packed Q/K/V (EPI3)
    gemm3_kernel<3, bf16><<<(1152 / 128) * (ROWS / 128), 256, 0, stream>>>(
        regB, wqkvT, (bf16*)nullptr, nullptr, nullptr, 1152 / 128, 1152, D_MODEL,
        Qpack, Kpack, Vpack);
    // 3. attention -> regB  (512 blocks x 512 threads; 2 blocks/CU exactly)
    attn_kernel<<<512, 512, 0, stream>>>(Qpack, Kpack, Vpack, Btab, regB);
    // 4. x1 = attn @ w_out + b_out + x -> d_out (f32)
    gemm3_kernel<1, float><<<(D_MODEL / 128) * (ROWS / 128), 256, 0, stream>>>(
        regB, woutT, x1, b_out, x, D_MODEL / 128, D_MODEL, D_MODEL,
        nullptr, nullptr, nullptr);
    // 5. LN2 -> regB
    ln_kernel<<<ROWS / 4, 256, 0, stream>>>(x1, ln2_w, ln2_b, regB);
    // 6. gelu(h2 @ w1 + b1) -> regA (packs dead now)
    gemm3_kernel<2, bf16><<<(HID / 128) * (ROWS / 128), 256, 0, stream>>>(
        regB, w1T, regA, b1, nullptr, HID / 128, HID, D_MODEL,
        nullptr, nullptr, nullptr);
    // 7. out = gelu @ w2 + b2 + x1
    gemm3_kernel<1, float><<<(D_MODEL / 128) * (ROWS / 128), 256, 0, stream>>>(
        regA, w2T, out, b2, x1, D_MODEL / 128, D_MODEL, HID,
        nullptr, nullptr, nullptr);
}